// Round 1
// baseline (289.895 us; speedup 1.0000x reference)
//
#include <hip/hip_runtime.h>

// InductionNetwork capsule routing, C=256, K=64, H=1024, 3 iterations.
// R8: Q = W^T W trick. u = W^T squash(W s) = scale * (Q s), with
// norm = ||W s||^2 = s . (Q s). This collapses each of iterations 0/1
// from {gemm, squash, gemm} to a single gemm(Q); the squash scale moves
// into a cheap routing prologue. Dispatches 12 -> 8:
//   D1 convert_wt             W -> Wt split-bf16 (transposed)
//   D2 routing0 || gemm_Q     enc -> s ; Q = Wt Wt^T (32x32/wave tiles)
//   D3 gemm_y || conv_Wb      y = Q s ; W -> Wb split (Wt buffer reused)
//   D4 routing1               norm=s.y, scale, b = scale*(E.y); s
//   D5 gemm_y                 y = Q s
//   D6 routing2               b += scale*(E.y); s
//   D7 gemm_chat              chat = W s  (B = Wb)
//   D8 squash_out             out = squash(chat)
// Split-bf16 operands (verified R6/R7): D = Ah.Bh + Ah.Bl + Al.Bh.
// Fragment layout verified R4/R6/R7: A[m=lane&15][k=(lane>>4)*8+j];
// C/D col=lane&15, row=(lane>>4)*4+reg.
// Fallback: R3's proven monolithic kernel if ws too small.

using f32x4  = __attribute__((ext_vector_type(4))) float;
using f32x2  = __attribute__((ext_vector_type(2))) float;
using bf16x8 = __attribute__((ext_vector_type(8))) __bf16;
using bf16x4 = __attribute__((ext_vector_type(4))) __bf16;

struct BfPair { __bf16 hi, lo; };
__device__ inline BfPair split_bf16(float x) {
    BfPair p;
    p.hi = (__bf16)x;
    p.lo = (__bf16)(x - (float)p.hi);
    return p;
}

// ---------------- routing body: prologue + b-update + softmax + wsum -------
// One block per capsule, 1024 threads = 16 waves. Wave w owns enc rows
// w*4..w*4+3; lane holds 16 floats/row. MODE 0: d uniform (iter 0).
// MODE 1: b = scale*(E.y) (store). MODE 2: b += scale*(E.y).
// Prologue (MODE>0): norm = sum(s*y) -> scale; y staged to LDS as u.
template <int MODE>
__device__ __forceinline__ void routing_body(
    const float* __restrict__ enc, const float* __restrict__ y0,
    const float* __restrict__ y1, float* __restrict__ bglob,
    __bf16* __restrict__ s_hi, __bf16* __restrict__ s_lo,
    float (*spart)[1024], float* u_s, float* b_s, float* d_s,
    float* red_s, float* scale_s)
{
    const int t = threadIdx.x, lane = t & 63, w = t >> 6;   // 16 waves
    const int c = blockIdx.x;
    const float* E = enc + (size_t)c * 65536;

    // small prologue loads first so their waitcnt doesn't drain er loads
    float yv = 0.f, sv = 0.f;
    if (MODE > 0) {
        const size_t o = (size_t)c * 1024 + t;
        yv = y0[o] + y1[o];                       // y = Q s (full K)
        sv = (float)s_hi[o] + (float)s_lo[o];     // s as the gemm saw it
    }

    f32x4 er[4][4];                     // 64 VGPRs of enc
    #pragma unroll
    for (int r = 0; r < 4; ++r) {
        const float* ek = E + (size_t)(w * 4 + r) * 1024 + lane * 8;
        er[r][0] = *(const f32x4*)(ek);
        er[r][1] = *(const f32x4*)(ek + 4);
        er[r][2] = *(const f32x4*)(ek + 512);
        er[r][3] = *(const f32x4*)(ek + 516);
    }

    if (MODE > 0) {
        u_s[t] = yv;
        float p = yv * sv;                        // norm = s^T Q s = |W s|^2
        #pragma unroll
        for (int off = 32; off; off >>= 1) p += __shfl_xor(p, off, 64);
        if (lane == 0) red_s[w] = p;
        __syncthreads();
        if (t == 0) {
            float n = 0.f;
            #pragma unroll
            for (int i = 0; i < 16; ++i) n += red_s[i];
            *scale_s = n / ((1.f + n) * sqrtf(n) + 1e-30f);
        }
        __syncthreads();
        const float scale = *scale_s;
        f32x4 uf[4];
        uf[0] = *(const f32x4*)&u_s[lane * 8];
        uf[1] = *(const f32x4*)&u_s[lane * 8 + 4];
        uf[2] = *(const f32x4*)&u_s[512 + lane * 8];
        uf[3] = *(const f32x4*)&u_s[512 + lane * 8 + 4];
        #pragma unroll
        for (int r = 0; r < 4; ++r) {
            float sum = 0.f;
            #pragma unroll
            for (int q = 0; q < 4; ++q)
                #pragma unroll
                for (int j = 0; j < 4; ++j)
                    sum += er[r][q][j] * uf[q][j];
            #pragma unroll
            for (int off = 32; off; off >>= 1) sum += __shfl_xor(sum, off, 64);
            if (lane == 0) {
                const int k = w * 4 + r;
                const float bv =
                    (MODE == 2 ? bglob[c * 64 + k] : 0.f) + scale * sum;
                bglob[c * 64 + k] = bv;     // persist for next iteration
                b_s[k] = bv;
            }
        }
    }
    __syncthreads();

    if (MODE == 0) {
        if (t < 64) d_s[t] = 1.f / 64.f;
    } else if (t < 64) {
        float bv = b_s[t], m = bv;
        #pragma unroll
        for (int off = 32; off; off >>= 1) m = fmaxf(m, __shfl_xor(m, off, 64));
        const float e = expf(bv - m);
        float sm = e;
        #pragma unroll
        for (int off = 32; off; off >>= 1) sm += __shfl_xor(sm, off, 64);
        d_s[t] = e / sm;
    }
    __syncthreads();

    // per-wave partial s from registers (4 rows each)
    #pragma unroll
    for (int q = 0; q < 4; ++q) {
        f32x4 p = {};
        #pragma unroll
        for (int r = 0; r < 4; ++r) {
            const float dk = d_s[w * 4 + r];
            #pragma unroll
            for (int j = 0; j < 4; ++j) p[j] += dk * er[r][q][j];
        }
        const int h = (q >> 1) * 512 + lane * 8 + (q & 1) * 4;
        *(f32x4*)&spart[w][h] = p;
    }
    __syncthreads();

    // cross-wave reduce: 1 h-element per thread; emit split-bf16 s
    {
        float a = 0.f;
        #pragma unroll
        for (int wv = 0; wv < 16; ++wv) a += spart[wv][t];
        const BfPair p = split_bf16(a);
        s_hi[(size_t)c * 1024 + t] = p.hi;
        s_lo[(size_t)c * 1024 + t] = p.lo;
    }
}

// ---- Q = Wt Wt^T (= W^T W), 32x32 output per wave, full K=1024.
// 1024 tasks; epilogue writes split-bf16 Q directly.
__device__ __forceinline__ void gemm_q_body(
    const __bf16* __restrict__ Wt_hi, const __bf16* __restrict__ Wt_lo,
    __bf16* __restrict__ Q_hi, __bf16* __restrict__ Q_lo, int task, int lane)
{
    const int i = task >> 5, j = task & 31;       // 32x32 tile grid
    const int kq = (lane >> 4) * 8;
    const size_t a0 = (size_t)(i * 32 + (lane & 15)) * 1024 + kq;
    const size_t a1 = a0 + 16 * 1024;
    const size_t b0 = (size_t)(j * 32 + (lane & 15)) * 1024 + kq;
    const size_t b1 = b0 + 16 * 1024;

    f32x4 acc[2][2] = {};
    #pragma unroll 2
    for (int k0 = 0; k0 < 1024; k0 += 32) {
        bf16x8 ah[2], al[2], bh[2], bl[2];
        ah[0] = *(const bf16x8*)(Wt_hi + a0 + k0);
        ah[1] = *(const bf16x8*)(Wt_hi + a1 + k0);
        al[0] = *(const bf16x8*)(Wt_lo + a0 + k0);
        al[1] = *(const bf16x8*)(Wt_lo + a1 + k0);
        bh[0] = *(const bf16x8*)(Wt_hi + b0 + k0);
        bh[1] = *(const bf16x8*)(Wt_hi + b1 + k0);
        bl[0] = *(const bf16x8*)(Wt_lo + b0 + k0);
        bl[1] = *(const bf16x8*)(Wt_lo + b1 + k0);
        #pragma unroll
        for (int mi = 0; mi < 2; ++mi)
            #pragma unroll
            for (int ni = 0; ni < 2; ++ni) {
                f32x4 a = acc[mi][ni];
                a = __builtin_amdgcn_mfma_f32_16x16x32_bf16(ah[mi], bh[ni], a, 0, 0, 0);
                a = __builtin_amdgcn_mfma_f32_16x16x32_bf16(ah[mi], bl[ni], a, 0, 0, 0);
                a = __builtin_amdgcn_mfma_f32_16x16x32_bf16(al[mi], bh[ni], a, 0, 0, 0);
                acc[mi][ni] = a;
            }
    }
    const int rr = (lane >> 4) * 4, colb = lane & 15;
    #pragma unroll
    for (int mi = 0; mi < 2; ++mi)
        #pragma unroll
        for (int ni = 0; ni < 2; ++ni)
            #pragma unroll
            for (int r = 0; r < 4; ++r) {
                const BfPair p = split_bf16(acc[mi][ni][r]);
                const size_t idx =
                    (size_t)(i * 32 + mi * 16 + rr + r) * 1024 +
                    j * 32 + ni * 16 + colb;
                Q_hi[idx] = p.hi;
                Q_lo[idx] = p.lo;
            }
}

// Merged dispatch: blocks [0,256) = routing capsule c; with WITH_Q, blocks
// [256,320) run gemm_Q as 16 waves/block (tasks (bx-256)*16+w over 1024).
template <int MODE, int WITH_Q>
__global__ __launch_bounds__(1024) void routing_q_kernel(
    const float* __restrict__ enc, const float* __restrict__ y0,
    const float* __restrict__ y1, float* __restrict__ bglob,
    __bf16* __restrict__ s_hi, __bf16* __restrict__ s_lo,
    const __bf16* __restrict__ Wt_hi, const __bf16* __restrict__ Wt_lo,
    __bf16* __restrict__ Q_hi, __bf16* __restrict__ Q_lo)
{
    __shared__ float spart[16][1024];   // 64 KB: per-wave partial s
    __shared__ float u_s[1024];         // 4 KB: y staged for the dots
    __shared__ float b_s[64], d_s[64], red_s[16], scale_s;

    if (WITH_Q && blockIdx.x >= 256) {
        const int w = threadIdx.x >> 6, lane = threadIdx.x & 63;
        gemm_q_body(Wt_hi, Wt_lo, Q_hi, Q_lo,
                    (blockIdx.x - 256) * 16 + w, lane);
        return;
    }
    routing_body<MODE>(enc, y0, y1, bglob, s_hi, s_lo,
                       spart, u_s, b_s, d_s, red_s, &scale_s);
}

// ---- split-bf16 NT GEMM, split-K x2: 2048 waves as 512 blocks x 4 waves.
// Wave gw: task=gw>>1 (mt=task>>6, nt=task&63), K-half kh=gw&1.
// With CONV, blocks [512,768) convert W fp32 -> split-bf16 Wd (coalesced).
template <int CONV>
__global__ __launch_bounds__(256) void gemm_split_kernel(
    const __bf16* __restrict__ Ah, const __bf16* __restrict__ Al,
    const __bf16* __restrict__ Bh, const __bf16* __restrict__ Bl,
    float* __restrict__ C0, float* __restrict__ C1,
    const float* __restrict__ Wsrc, __bf16* __restrict__ Wd_hi,
    __bf16* __restrict__ Wd_lo)
{
    if (CONV && blockIdx.x >= 512) {
        const int b = blockIdx.x - 512;             // 0..255
        const size_t base = (size_t)b * 4096 + (threadIdx.x << 2);
        #pragma unroll
        for (int q = 0; q < 4; ++q) {
            const size_t idx = base + (size_t)q * 1024;
            const f32x4 v = *(const f32x4*)(Wsrc + idx);
            bf16x4 hv, lv;
            #pragma unroll
            for (int j = 0; j < 4; ++j) {
                const BfPair p = split_bf16(v[j]);
                hv[j] = p.hi;
                lv[j] = p.lo;
            }
            *(bf16x4*)(Wd_hi + idx) = hv;
            *(bf16x4*)(Wd_lo + idx) = lv;
        }
        return;
    }

    const int w = threadIdx.x >> 6;
    const int gw = blockIdx.x * 4 + w;
    const int task = gw >> 1;
    const int kh   = gw & 1;
    const int mt   = task >> 6;
    const int nt   = task & 63;
    const int lane = threadIdx.x & 63;
    const int kq   = (lane >> 4) * 8 + kh * 512;
    const size_t aoff = (size_t)(mt * 16 + (lane & 15)) * 1024 + kq;
    const size_t boff = (size_t)(nt * 16 + (lane & 15)) * 1024 + kq;

    f32x4 hh = {}, hl = {}, lh = {};
    #pragma unroll 4
    for (int k0 = 0; k0 < 512; k0 += 32) {
        bf16x8 ah = *(const bf16x8*)(Ah + aoff + k0);
        bf16x8 al = *(const bf16x8*)(Al + aoff + k0);
        bf16x8 bh = *(const bf16x8*)(Bh + boff + k0);
        bf16x8 bl = *(const bf16x8*)(Bl + boff + k0);
        hh = __builtin_amdgcn_mfma_f32_16x16x32_bf16(ah, bh, hh, 0, 0, 0);
        hl = __builtin_amdgcn_mfma_f32_16x16x32_bf16(ah, bl, hl, 0, 0, 0);
        lh = __builtin_amdgcn_mfma_f32_16x16x32_bf16(al, bh, lh, 0, 0, 0);
    }
    f32x4 acc = hh + hl + lh;
    float* Cc = kh ? C1 : C0;
    const int rr = (lane >> 4) * 4, colb = lane & 15;
    #pragma unroll
    for (int r = 0; r < 4; ++r)
        Cc[(size_t)(mt * 16 + rr + r) * 1024 + nt * 16 + colb] = acc[r];
}

// ---------------- final squash: sums split-K chat, emits out ---------------
__global__ __launch_bounds__(256) void squash_out_kernel(
    const float* __restrict__ chat0, const float* __restrict__ chat1,
    float* __restrict__ outp)
{
    __shared__ float wsum[4];
    const int c = blockIdx.x, t = threadIdx.x;
    const int lane = t & 63, w = t >> 6;
    const size_t o = (size_t)c * 1024 + t * 4;
    f32x4 v = *(const f32x4*)(chat0 + o) + *(const f32x4*)(chat1 + o);
    float ss = v[0]*v[0] + v[1]*v[1] + v[2]*v[2] + v[3]*v[3];
    #pragma unroll
    for (int off = 32; off; off >>= 1) ss += __shfl_xor(ss, off, 64);
    if (lane == 0) wsum[w] = ss;
    __syncthreads();
    const float norm = wsum[0] + wsum[1] + wsum[2] + wsum[3];
    const float scale = norm / ((1.f + norm) * sqrtf(norm) + 1e-30f);
    *(f32x4*)(outp + o) = v * scale;
}

// ---------------- W -> split bf16 transposed (for Q-GEMM) ------------------
__global__ __launch_bounds__(256) void convert_wt_kernel(
    const float* __restrict__ W, __bf16* __restrict__ Wt_hi,
    __bf16* __restrict__ Wt_lo)
{
    __shared__ float tile[64][65];
    const int bx = blockIdx.x, by = blockIdx.y;
    const int tx = threadIdx.x & 63, ty = threadIdx.x >> 6;
    for (int i = ty; i < 64; i += 4)
        tile[i][tx] = W[(size_t)(by * 64 + i) * 1024 + bx * 64 + tx];
    __syncthreads();
    for (int i = ty; i < 64; i += 4) {
        const size_t idx = (size_t)(bx * 64 + i) * 1024 + by * 64 + tx;
        const BfPair p = split_bf16(tile[tx][i]);
        Wt_hi[idx] = p.hi;
        Wt_lo[idx] = p.lo;
    }
}

// ---------------- fallback: R3's proven monolithic fp32 kernel --------------
__global__ __launch_bounds__(512) void fallback_kernel(
    const float* __restrict__ enc, const float* __restrict__ W,
    float* __restrict__ outp)
{
    __shared__ float u_s[1024], s_s[1024], c_s[1024], chat_s[1024];
    __shared__ float b_s[64], d_s[64], red_s[8];
    const int t = threadIdx.x, lane = t & 63, w = t >> 6;
    const float* erow = enc + (size_t)blockIdx.x * 65536;

    if (t < 64) b_s[t] = 0.f;
    __syncthreads();

    for (int it = 0; it < 3; ++it) {
        if (it > 0) {
            f32x4 uf[4];
            #pragma unroll
            for (int q = 0; q < 2; ++q) {
                uf[2*q]   = *(const f32x4*)&u_s[q*512 + lane*8];
                uf[2*q+1] = *(const f32x4*)&u_s[q*512 + lane*8 + 4];
            }
            for (int r = 0; r < 8; ++r) {
                const int k = w * 8 + r;
                const float* ek = erow + (size_t)k * 1024;
                float sum = 0.f;
                #pragma unroll
                for (int q = 0; q < 2; ++q) {
                    f32x4 e0 = *(const f32x4*)(ek + q*512 + lane*8);
                    f32x4 e1 = *(const f32x4*)(ek + q*512 + lane*8 + 4);
                    #pragma unroll
                    for (int j = 0; j < 4; ++j) {
                        sum += e0[j] * uf[2*q][j];
                        sum += e1[j] * uf[2*q+1][j];
                    }
                }
                #pragma unroll
                for (int off = 32; off; off >>= 1) sum += __shfl_xor(sum, off, 64);
                if (lane == 0) b_s[k] += sum;
            }
            __syncthreads();
        }
        if (t < 64) {
            float bv = b_s[t], m = bv;
            #pragma unroll
            for (int off = 32; off; off >>= 1) m = fmaxf(m, __shfl_xor(m, off, 64));
            float e = expf(bv - m), sm = e;
            #pragma unroll
            for (int off = 32; off; off >>= 1) sm += __shfl_xor(sm, off, 64);
            d_s[t] = e / sm;
        }
        __syncthreads();
        {
            const int h0 = t * 2;
            float a0 = 0.f, a1 = 0.f;
            for (int k = 0; k < 64; ++k) {
                f32x2 ev = *(const f32x2*)(erow + (size_t)k * 1024 + h0);
                a0 += d_s[k] * ev[0]; a1 += d_s[k] * ev[1];
            }
            s_s[h0] = a0; s_s[h0+1] = a1;
        }
        __syncthreads();
        {
            f32x4 sf[4];
            #pragma unroll
            for (int q = 0; q < 2; ++q) {
                sf[2*q]   = *(const f32x4*)&s_s[q*512 + lane*8];
                sf[2*q+1] = *(const f32x4*)&s_s[q*512 + lane*8 + 4];
            }
            for (int r = 0; r < 128; ++r) {
                const int d = w * 128 + r;
                const float* wr = W + (size_t)d * 1024;
                float sum = 0.f;
                #pragma unroll
                for (int q = 0; q < 2; ++q) {
                    f32x4 w0 = *(const f32x4*)(wr + q*512 + lane*8);
                    f32x4 w1 = *(const f32x4*)(wr + q*512 + lane*8 + 4);
                    #pragma unroll
                    for (int j = 0; j < 4; ++j) {
                        sum += w0[j] * sf[2*q][j];
                        sum += w1[j] * sf[2*q+1][j];
                    }
                }
                #pragma unroll
                for (int off = 32; off; off >>= 1) sum += __shfl_xor(sum, off, 64);
                if (lane == 0) chat_s[d] = sum;
            }
        }
        __syncthreads();
        {
            const int h0 = t * 2;
            float v0 = chat_s[h0], v1 = chat_s[h0+1];
            float ss = v0*v0 + v1*v1;
            #pragma unroll
            for (int off = 32; off; off >>= 1) ss += __shfl_xor(ss, off, 64);
            if (lane == 0) red_s[w] = ss;
            __syncthreads();
            float norm = 0.f;
            #pragma unroll
            for (int i = 0; i < 8; ++i) norm += red_s[i];
            const float scale = norm / ((1.f + norm) * sqrtf(norm) + 1e-30f);
            c_s[h0] = v0 * scale; c_s[h0+1] = v1 * scale;
        }
        __syncthreads();
        if (it < 2) {
            const int h0 = t * 2;
            float uu0 = 0.f, uu1 = 0.f;
            for (int d = 0; d < 1024; ++d) {
                f32x2 wv = *(const f32x2*)(W + (size_t)d * 1024 + h0);
                uu0 += c_s[d] * wv[0]; uu1 += c_s[d] * wv[1];
            }
            u_s[h0] = uu0; u_s[h0+1] = uu1;
        } else {
            const int h0 = t * 2;
            f32x2 ov; ov[0] = c_s[h0]; ov[1] = c_s[h0+1];
            *(f32x2*)(outp + (size_t)blockIdx.x * 1024 + h0) = ov;
        }
        __syncthreads();
    }
}

extern "C" void kernel_launch(void* const* d_in, const int* in_sizes, int n_in,
                              void* d_out, int out_size, void* d_ws, size_t ws_size,
                              hipStream_t stream)
{
    const float* enc = (const float*)d_in[0];   // [256,64,1024] fp32
    const float* W   = (const float*)d_in[1];   // [1024,1024]   fp32
    float* outp = (float*)d_out;                // [256,1024]    fp32
    (void)in_sizes; (void)n_in; (void)out_size;

    // ws layout (11.5 MB)
    char* ws = (char*)d_ws;
    float*  b     = (float*) (ws + 0x000000);  //  64 KB [256,64]
    __bf16* s_hi  = (__bf16*)(ws + 0x080000);  // 512 KB [256,1024]
    __bf16* s_lo  = (__bf16*)(ws + 0x100000);  // 512 KB
    float*  y0    = (float*) (ws + 0x180000);  //   1 MB (y / chat, split-K lo)
    float*  y1    = (float*) (ws + 0x280000);  //   1 MB (y / chat, split-K hi)
    __bf16* Wx_hi = (__bf16*)(ws + 0x380000);  //   2 MB  Wt then Wb (reuse)
    __bf16* Wx_lo = (__bf16*)(ws + 0x580000);  //   2 MB
    __bf16* Q_hi  = (__bf16*)(ws + 0x780000);  //   2 MB [1024,1024]
    __bf16* Q_lo  = (__bf16*)(ws + 0x980000);  //   2 MB

    if (ws_size < 0xB80000) {
        fallback_kernel<<<256, 512, 0, stream>>>(enc, W, outp);
        return;
    }

    // D1: W -> Wt split-bf16 (transposed layout, feeds Q-GEMM)
    convert_wt_kernel<<<dim3(16, 16), 256, 0, stream>>>(W, Wx_hi, Wx_lo);

    // D2: routing iter0 (s = mean_k enc) || Q = Wt Wt^T
    routing_q_kernel<0, 1><<<320, 1024, 0, stream>>>(
        enc, y0, y1, b, s_hi, s_lo, Wx_hi, Wx_lo, Q_hi, Q_lo);

    // D3: y = Q s  || convert W -> Wb into the (now dead) Wt buffer
    gemm_split_kernel<1><<<768, 256, 0, stream>>>(
        s_hi, s_lo, Q_hi, Q_lo, y0, y1, W, Wx_hi, Wx_lo);

    // D4: routing iter1 (norm = s.y, scale; b = scale*(E.y); new s)
    routing_q_kernel<1, 0><<<256, 1024, 0, stream>>>(
        enc, y0, y1, b, s_hi, s_lo, Wx_hi, Wx_lo, Q_hi, Q_lo);

    // D5: y = Q s
    gemm_split_kernel<0><<<512, 256, 0, stream>>>(
        s_hi, s_lo, Q_hi, Q_lo, y0, y1, nullptr, nullptr, nullptr);

    // D6: routing iter2 (b += scale*(E.y); final s)
    routing_q_kernel<2, 0><<<256, 1024, 0, stream>>>(
        enc, y0, y1, b, s_hi, s_lo, Wx_hi, Wx_lo, Q_hi, Q_lo);

    // D7: chat = W s   (B = Wb, now in Wx)
    gemm_split_kernel<0><<<512, 256, 0, stream>>>(
        s_hi, s_lo, Wx_hi, Wx_lo, y0, y1, nullptr, nullptr, nullptr);

    // D8: out = squash(chat)
    squash_out_kernel<<<256, 256, 0, stream>>>(y0, y1, outp);
}

// Round 2
// 247.348 us; speedup vs baseline: 1.1720x; 1.1720x over previous
//
#include <hip/hip_runtime.h>

// InductionNetwork capsule routing, C=256, K=64, H=1024, 3 iterations.
// R9: same 8-dispatch Q = W^T W pipeline as R8, but the Q-GEMM is now
// LDS-staged. R8 post-mortem: per-wave 32x32 tiles with K=1024 direct
// from global issued 256 MB of cache traffic concentrated on ~64 CUs ->
// D2 took 126us (390 GB/s, MfmaUtil 1.9%). R9 Q-GEMM: 64 blocks x 16
// waves, 128x128 tile, BK=64 LDS staging with XOR swizzle
// (byte ^= (row&7)<<4) -> 64 MB total traffic, block-level reuse.
// Dispatches:
//   D1 convert_wt             W -> Wt split-bf16 (transposed)
//   D2 routing0 || gemm_Q     enc -> s ; Q = Wt Wt^T (128x128 LDS tiles)
//   D3 gemm_y || conv_Wb      y = Q s ; W -> Wb split (Wt buffer reused)
//   D4 routing1               norm=s.y, scale, b = scale*(E.y); s
//   D5 gemm_y                 y = Q s
//   D6 routing2               b += scale*(E.y); s
//   D7 gemm_chat              chat = W s  (B = Wb)
//   D8 squash_out             out = squash(chat)
// Split-bf16 operands (verified R6-R8, absmax 4.88e-4):
//   D = Ah.Bh + Ah.Bl + Al.Bh with hi=bf16(x), lo=bf16(x-hi).
// Fragment layout verified R4/R6/R7: A[m=lane&15][k=(lane>>4)*8+j];
// C/D col=lane&15, row=(lane>>4)*4+reg.
// Fallback: R3's proven monolithic kernel if ws too small.

using f32x4  = __attribute__((ext_vector_type(4))) float;
using f32x2  = __attribute__((ext_vector_type(2))) float;
using bf16x8 = __attribute__((ext_vector_type(8))) __bf16;
using bf16x4 = __attribute__((ext_vector_type(4))) __bf16;

struct BfPair { __bf16 hi, lo; };
__device__ inline BfPair split_bf16(float x) {
    BfPair p;
    p.hi = (__bf16)x;
    p.lo = (__bf16)(x - (float)p.hi);
    return p;
}

// ---------------- routing body: prologue + b-update + softmax + wsum -------
// One block per capsule, 1024 threads = 16 waves. Wave w owns enc rows
// w*4..w*4+3; lane holds 16 floats/row. MODE 0: d uniform (iter 0).
// MODE 1: b = scale*(E.y) (store). MODE 2: b += scale*(E.y).
// Prologue (MODE>0): norm = sum(s*y) -> scale; y staged to LDS as u.
template <int MODE>
__device__ __forceinline__ void routing_body(
    const float* __restrict__ enc, const float* __restrict__ y0,
    const float* __restrict__ y1, float* __restrict__ bglob,
    __bf16* __restrict__ s_hi, __bf16* __restrict__ s_lo,
    float (*spart)[1024], float* u_s, float* b_s, float* d_s,
    float* red_s, float* scale_s)
{
    const int t = threadIdx.x, lane = t & 63, w = t >> 6;   // 16 waves
    const int c = blockIdx.x;
    const float* E = enc + (size_t)c * 65536;

    // small prologue loads first so their waitcnt doesn't drain er loads
    float yv = 0.f, sv = 0.f;
    if (MODE > 0) {
        const size_t o = (size_t)c * 1024 + t;
        yv = y0[o] + y1[o];                       // y = Q s (full K)
        sv = (float)s_hi[o] + (float)s_lo[o];     // s as the gemm saw it
    }

    f32x4 er[4][4];                     // 64 VGPRs of enc
    #pragma unroll
    for (int r = 0; r < 4; ++r) {
        const float* ek = E + (size_t)(w * 4 + r) * 1024 + lane * 8;
        er[r][0] = *(const f32x4*)(ek);
        er[r][1] = *(const f32x4*)(ek + 4);
        er[r][2] = *(const f32x4*)(ek + 512);
        er[r][3] = *(const f32x4*)(ek + 516);
    }

    if (MODE > 0) {
        u_s[t] = yv;
        float p = yv * sv;                        // norm = s^T Q s = |W s|^2
        #pragma unroll
        for (int off = 32; off; off >>= 1) p += __shfl_xor(p, off, 64);
        if (lane == 0) red_s[w] = p;
        __syncthreads();
        if (t == 0) {
            float n = 0.f;
            #pragma unroll
            for (int i = 0; i < 16; ++i) n += red_s[i];
            *scale_s = n / ((1.f + n) * sqrtf(n) + 1e-30f);
        }
        __syncthreads();
        const float scale = *scale_s;
        f32x4 uf[4];
        uf[0] = *(const f32x4*)&u_s[lane * 8];
        uf[1] = *(const f32x4*)&u_s[lane * 8 + 4];
        uf[2] = *(const f32x4*)&u_s[512 + lane * 8];
        uf[3] = *(const f32x4*)&u_s[512 + lane * 8 + 4];
        #pragma unroll
        for (int r = 0; r < 4; ++r) {
            float sum = 0.f;
            #pragma unroll
            for (int q = 0; q < 4; ++q)
                #pragma unroll
                for (int j = 0; j < 4; ++j)
                    sum += er[r][q][j] * uf[q][j];
            #pragma unroll
            for (int off = 32; off; off >>= 1) sum += __shfl_xor(sum, off, 64);
            if (lane == 0) {
                const int k = w * 4 + r;
                const float bv =
                    (MODE == 2 ? bglob[c * 64 + k] : 0.f) + scale * sum;
                bglob[c * 64 + k] = bv;     // persist for next iteration
                b_s[k] = bv;
            }
        }
    }
    __syncthreads();

    if (MODE == 0) {
        if (t < 64) d_s[t] = 1.f / 64.f;
    } else if (t < 64) {
        float bv = b_s[t], m = bv;
        #pragma unroll
        for (int off = 32; off; off >>= 1) m = fmaxf(m, __shfl_xor(m, off, 64));
        const float e = expf(bv - m);
        float sm = e;
        #pragma unroll
        for (int off = 32; off; off >>= 1) sm += __shfl_xor(sm, off, 64);
        d_s[t] = e / sm;
    }
    __syncthreads();

    // per-wave partial s from registers (4 rows each)
    #pragma unroll
    for (int q = 0; q < 4; ++q) {
        f32x4 p = {};
        #pragma unroll
        for (int r = 0; r < 4; ++r) {
            const float dk = d_s[w * 4 + r];
            #pragma unroll
            for (int j = 0; j < 4; ++j) p[j] += dk * er[r][q][j];
        }
        const int h = (q >> 1) * 512 + lane * 8 + (q & 1) * 4;
        *(f32x4*)&spart[w][h] = p;
    }
    __syncthreads();

    // cross-wave reduce: 1 h-element per thread; emit split-bf16 s
    {
        float a = 0.f;
        #pragma unroll
        for (int wv = 0; wv < 16; ++wv) a += spart[wv][t];
        const BfPair p = split_bf16(a);
        s_hi[(size_t)c * 1024 + t] = p.hi;
        s_lo[(size_t)c * 1024 + t] = p.lo;
    }
}

// ---- Q = Wt Wt^T (= W^T W): 64 blocks x 16 waves, 128x128 tile, BK=64
// LDS staging (Ah/Al/Bh/Bl 16 KB each), XOR-swizzled rows. Wave (wr,wc)
// in 4x4 grid owns a 32x32 sub-tile (2x2 MFMA frags). Epilogue writes
// split-bf16 Q directly.
struct QSmem {
    __bf16 a_hi[128 * 64];
    __bf16 a_lo[128 * 64];
    __bf16 b_hi[128 * 64];
    __bf16 b_lo[128 * 64];
};

__device__ __forceinline__ int swz128(int row, int colbyte) {
    // 128-byte rows; XOR bits 4-6 of the byte offset with row&7
    return row * 128 + (colbyte ^ ((row & 7) << 4));
}

__device__ __forceinline__ void gemm_q_body(
    const __bf16* __restrict__ Wt_hi, const __bf16* __restrict__ Wt_lo,
    __bf16* __restrict__ Q_hi, __bf16* __restrict__ Q_lo, QSmem* sm, int qb)
{
    const int ti = qb >> 3, tj = qb & 7;        // 8x8 grid of 128x128 tiles
    const int t = threadIdx.x;
    const int lane = t & 63, w = t >> 6;
    const int wr = w >> 2, wc = w & 3;          // wave's 32x32 sub-tile
    // staging coords: thread loads one 16B chunk per buffer per step
    const int sr = t >> 3;                      // row 0..127
    const int scb = (t & 7) * 16;               // col byte 0..112
    const size_t ga = (size_t)(ti * 128 + sr) * 1024 + scb / 2;
    const size_t gb = (size_t)(tj * 128 + sr) * 1024 + scb / 2;
    char* const pa_hi = (char*)sm->a_hi + swz128(sr, scb);
    char* const pa_lo = (char*)sm->a_lo + swz128(sr, scb);
    char* const pb_hi = (char*)sm->b_hi + swz128(sr, scb);
    char* const pb_lo = (char*)sm->b_lo + swz128(sr, scb);

    f32x4 acc[2][2] = {};
    for (int k0 = 0; k0 < 1024; k0 += 64) {
        if (k0) __syncthreads();                // prev step's reads done
        *(bf16x8*)pa_hi = *(const bf16x8*)(Wt_hi + ga + k0);
        *(bf16x8*)pa_lo = *(const bf16x8*)(Wt_lo + ga + k0);
        *(bf16x8*)pb_hi = *(const bf16x8*)(Wt_hi + gb + k0);
        *(bf16x8*)pb_lo = *(const bf16x8*)(Wt_lo + gb + k0);
        __syncthreads();
        #pragma unroll
        for (int kk = 0; kk < 2; ++kk) {
            const int cb = kk * 64 + (lane >> 4) * 16;  // col byte of frag
            bf16x8 ah[2], al[2], bh[2], bl[2];
            #pragma unroll
            for (int mi = 0; mi < 2; ++mi) {
                const int m = wr * 32 + mi * 16 + (lane & 15);
                ah[mi] = *(const bf16x8*)((char*)sm->a_hi + swz128(m, cb));
                al[mi] = *(const bf16x8*)((char*)sm->a_lo + swz128(m, cb));
            }
            #pragma unroll
            for (int ni = 0; ni < 2; ++ni) {
                const int n = wc * 32 + ni * 16 + (lane & 15);
                bh[ni] = *(const bf16x8*)((char*)sm->b_hi + swz128(n, cb));
                bl[ni] = *(const bf16x8*)((char*)sm->b_lo + swz128(n, cb));
            }
            #pragma unroll
            for (int mi = 0; mi < 2; ++mi)
                #pragma unroll
                for (int ni = 0; ni < 2; ++ni) {
                    f32x4 a = acc[mi][ni];
                    a = __builtin_amdgcn_mfma_f32_16x16x32_bf16(ah[mi], bh[ni], a, 0, 0, 0);
                    a = __builtin_amdgcn_mfma_f32_16x16x32_bf16(ah[mi], bl[ni], a, 0, 0, 0);
                    a = __builtin_amdgcn_mfma_f32_16x16x32_bf16(al[mi], bh[ni], a, 0, 0, 0);
                    acc[mi][ni] = a;
                }
        }
    }
    const int rr = (lane >> 4) * 4, colb = lane & 15;
    #pragma unroll
    for (int mi = 0; mi < 2; ++mi)
        #pragma unroll
        for (int ni = 0; ni < 2; ++ni)
            #pragma unroll
            for (int r = 0; r < 4; ++r) {
                const BfPair p = split_bf16(acc[mi][ni][r]);
                const size_t idx =
                    (size_t)(ti * 128 + wr * 32 + mi * 16 + rr + r) * 1024 +
                    tj * 128 + wc * 32 + ni * 16 + colb;
                Q_hi[idx] = p.hi;
                Q_lo[idx] = p.lo;
            }
}

// Merged dispatch: blocks [0,256) = routing capsule c; with WITH_Q, blocks
// [256,320) run gemm_Q (one 128x128 tile per block).
template <int MODE, int WITH_Q>
__global__ __launch_bounds__(1024) void routing_q_kernel(
    const float* __restrict__ enc, const float* __restrict__ y0,
    const float* __restrict__ y1, float* __restrict__ bglob,
    __bf16* __restrict__ s_hi, __bf16* __restrict__ s_lo,
    const __bf16* __restrict__ Wt_hi, const __bf16* __restrict__ Wt_lo,
    __bf16* __restrict__ Q_hi, __bf16* __restrict__ Q_lo)
{
    __shared__ union SM {
        struct {
            float spart[16][1024];  // 64 KB: per-wave partial s
            float u_s[1024];        //  4 KB: y staged for the dots
            float b_s[64], d_s[64], red_s[16], scale_s;
        } r;
        QSmem q;                    // 64 KB: Q staging tiles
    } sm;

    if (WITH_Q && blockIdx.x >= 256) {
        gemm_q_body(Wt_hi, Wt_lo, Q_hi, Q_lo, &sm.q, blockIdx.x - 256);
        return;
    }
    routing_body<MODE>(enc, y0, y1, bglob, s_hi, s_lo,
                       sm.r.spart, sm.r.u_s, sm.r.b_s, sm.r.d_s,
                       sm.r.red_s, &sm.r.scale_s);
}

// ---- split-bf16 NT GEMM, split-K x2: 2048 waves as 512 blocks x 4 waves.
// Wave gw: task=gw>>1 (mt=task>>6, nt=task&63), K-half kh=gw&1.
// With CONV, blocks [512,768) convert W fp32 -> split-bf16 Wd (coalesced).
template <int CONV>
__global__ __launch_bounds__(256) void gemm_split_kernel(
    const __bf16* __restrict__ Ah, const __bf16* __restrict__ Al,
    const __bf16* __restrict__ Bh, const __bf16* __restrict__ Bl,
    float* __restrict__ C0, float* __restrict__ C1,
    const float* __restrict__ Wsrc, __bf16* __restrict__ Wd_hi,
    __bf16* __restrict__ Wd_lo)
{
    if (CONV && blockIdx.x >= 512) {
        const int b = blockIdx.x - 512;             // 0..255
        const size_t base = (size_t)b * 4096 + (threadIdx.x << 2);
        #pragma unroll
        for (int q = 0; q < 4; ++q) {
            const size_t idx = base + (size_t)q * 1024;
            const f32x4 v = *(const f32x4*)(Wsrc + idx);
            bf16x4 hv, lv;
            #pragma unroll
            for (int j = 0; j < 4; ++j) {
                const BfPair p = split_bf16(v[j]);
                hv[j] = p.hi;
                lv[j] = p.lo;
            }
            *(bf16x4*)(Wd_hi + idx) = hv;
            *(bf16x4*)(Wd_lo + idx) = lv;
        }
        return;
    }

    const int w = threadIdx.x >> 6;
    const int gw = blockIdx.x * 4 + w;
    const int task = gw >> 1;
    const int kh   = gw & 1;
    const int mt   = task >> 6;
    const int nt   = task & 63;
    const int lane = threadIdx.x & 63;
    const int kq   = (lane >> 4) * 8 + kh * 512;
    const size_t aoff = (size_t)(mt * 16 + (lane & 15)) * 1024 + kq;
    const size_t boff = (size_t)(nt * 16 + (lane & 15)) * 1024 + kq;

    f32x4 hh = {}, hl = {}, lh = {};
    #pragma unroll 4
    for (int k0 = 0; k0 < 512; k0 += 32) {
        bf16x8 ah = *(const bf16x8*)(Ah + aoff + k0);
        bf16x8 al = *(const bf16x8*)(Al + aoff + k0);
        bf16x8 bh = *(const bf16x8*)(Bh + boff + k0);
        bf16x8 bl = *(const bf16x8*)(Bl + boff + k0);
        hh = __builtin_amdgcn_mfma_f32_16x16x32_bf16(ah, bh, hh, 0, 0, 0);
        hl = __builtin_amdgcn_mfma_f32_16x16x32_bf16(ah, bl, hl, 0, 0, 0);
        lh = __builtin_amdgcn_mfma_f32_16x16x32_bf16(al, bh, lh, 0, 0, 0);
    }
    f32x4 acc = hh + hl + lh;
    float* Cc = kh ? C1 : C0;
    const int rr = (lane >> 4) * 4, colb = lane & 15;
    #pragma unroll
    for (int r = 0; r < 4; ++r)
        Cc[(size_t)(mt * 16 + rr + r) * 1024 + nt * 16 + colb] = acc[r];
}

// ---------------- final squash: sums split-K chat, emits out ---------------
__global__ __launch_bounds__(256) void squash_out_kernel(
    const float* __restrict__ chat0, const float* __restrict__ chat1,
    float* __restrict__ outp)
{
    __shared__ float wsum[4];
    const int c = blockIdx.x, t = threadIdx.x;
    const int lane = t & 63, w = t >> 6;
    const size_t o = (size_t)c * 1024 + t * 4;
    f32x4 v = *(const f32x4*)(chat0 + o) + *(const f32x4*)(chat1 + o);
    float ss = v[0]*v[0] + v[1]*v[1] + v[2]*v[2] + v[3]*v[3];
    #pragma unroll
    for (int off = 32; off; off >>= 1) ss += __shfl_xor(ss, off, 64);
    if (lane == 0) wsum[w] = ss;
    __syncthreads();
    const float norm = wsum[0] + wsum[1] + wsum[2] + wsum[3];
    const float scale = norm / ((1.f + norm) * sqrtf(norm) + 1e-30f);
    *(f32x4*)(outp + o) = v * scale;
}

// ---------------- W -> split bf16 transposed (for Q-GEMM) ------------------
__global__ __launch_bounds__(256) void convert_wt_kernel(
    const float* __restrict__ W, __bf16* __restrict__ Wt_hi,
    __bf16* __restrict__ Wt_lo)
{
    __shared__ float tile[64][65];
    const int bx = blockIdx.x, by = blockIdx.y;
    const int tx = threadIdx.x & 63, ty = threadIdx.x >> 6;
    for (int i = ty; i < 64; i += 4)
        tile[i][tx] = W[(size_t)(by * 64 + i) * 1024 + bx * 64 + tx];
    __syncthreads();
    for (int i = ty; i < 64; i += 4) {
        const size_t idx = (size_t)(bx * 64 + i) * 1024 + by * 64 + tx;
        const BfPair p = split_bf16(tile[tx][i]);
        Wt_hi[idx] = p.hi;
        Wt_lo[idx] = p.lo;
    }
}

// ---------------- fallback: R3's proven monolithic fp32 kernel --------------
__global__ __launch_bounds__(512) void fallback_kernel(
    const float* __restrict__ enc, const float* __restrict__ W,
    float* __restrict__ outp)
{
    __shared__ float u_s[1024], s_s[1024], c_s[1024], chat_s[1024];
    __shared__ float b_s[64], d_s[64], red_s[8];
    const int t = threadIdx.x, lane = t & 63, w = t >> 6;
    const float* erow = enc + (size_t)blockIdx.x * 65536;

    if (t < 64) b_s[t] = 0.f;
    __syncthreads();

    for (int it = 0; it < 3; ++it) {
        if (it > 0) {
            f32x4 uf[4];
            #pragma unroll
            for (int q = 0; q < 2; ++q) {
                uf[2*q]   = *(const f32x4*)&u_s[q*512 + lane*8];
                uf[2*q+1] = *(const f32x4*)&u_s[q*512 + lane*8 + 4];
            }
            for (int r = 0; r < 8; ++r) {
                const int k = w * 8 + r;
                const float* ek = erow + (size_t)k * 1024;
                float sum = 0.f;
                #pragma unroll
                for (int q = 0; q < 2; ++q) {
                    f32x4 e0 = *(const f32x4*)(ek + q*512 + lane*8);
                    f32x4 e1 = *(const f32x4*)(ek + q*512 + lane*8 + 4);
                    #pragma unroll
                    for (int j = 0; j < 4; ++j) {
                        sum += e0[j] * uf[2*q][j];
                        sum += e1[j] * uf[2*q+1][j];
                    }
                }
                #pragma unroll
                for (int off = 32; off; off >>= 1) sum += __shfl_xor(sum, off, 64);
                if (lane == 0) b_s[k] += sum;
            }
            __syncthreads();
        }
        if (t < 64) {
            float bv = b_s[t], m = bv;
            #pragma unroll
            for (int off = 32; off; off >>= 1) m = fmaxf(m, __shfl_xor(m, off, 64));
            float e = expf(bv - m), sm = e;
            #pragma unroll
            for (int off = 32; off; off >>= 1) sm += __shfl_xor(sm, off, 64);
            d_s[t] = e / sm;
        }
        __syncthreads();
        {
            const int h0 = t * 2;
            float a0 = 0.f, a1 = 0.f;
            for (int k = 0; k < 64; ++k) {
                f32x2 ev = *(const f32x2*)(erow + (size_t)k * 1024 + h0);
                a0 += d_s[k] * ev[0]; a1 += d_s[k] * ev[1];
            }
            s_s[h0] = a0; s_s[h0+1] = a1;
        }
        __syncthreads();
        {
            f32x4 sf[4];
            #pragma unroll
            for (int q = 0; q < 2; ++q) {
                sf[2*q]   = *(const f32x4*)&s_s[q*512 + lane*8];
                sf[2*q+1] = *(const f32x4*)&s_s[q*512 + lane*8 + 4];
            }
            for (int r = 0; r < 128; ++r) {
                const int d = w * 128 + r;
                const float* wr = W + (size_t)d * 1024;
                float sum = 0.f;
                #pragma unroll
                for (int q = 0; q < 2; ++q) {
                    f32x4 w0 = *(const f32x4*)(wr + q*512 + lane*8);
                    f32x4 w1 = *(const f32x4*)(wr + q*512 + lane*8 + 4);
                    #pragma unroll
                    for (int j = 0; j < 4; ++j) {
                        sum += w0[j] * sf[2*q][j];
                        sum += w1[j] * sf[2*q+1][j];
                    }
                }
                #pragma unroll
                for (int off = 32; off; off >>= 1) sum += __shfl_xor(sum, off, 64);
                if (lane == 0) chat_s[d] = sum;
            }
        }
        __syncthreads();
        {
            const int h0 = t * 2;
            float v0 = chat_s[h0], v1 = chat_s[h0+1];
            float ss = v0*v0 + v1*v1;
            #pragma unroll
            for (int off = 32; off; off >>= 1) ss += __shfl_xor(ss, off, 64);
            if (lane == 0) red_s[w] = ss;
            __syncthreads();
            float norm = 0.f;
            #pragma unroll
            for (int i = 0; i < 8; ++i) norm += red_s[i];
            const float scale = norm / ((1.f + norm) * sqrtf(norm) + 1e-30f);
            c_s[h0] = v0 * scale; c_s[h0+1] = v1 * scale;
        }
        __syncthreads();
        if (it < 2) {
            const int h0 = t * 2;
            float uu0 = 0.f, uu1 = 0.f;
            for (int d = 0; d < 1024; ++d) {
                f32x2 wv = *(const f32x2*)(W + (size_t)d * 1024 + h0);
                uu0 += c_s[d] * wv[0]; uu1 += c_s[d] * wv[1];
            }
            u_s[h0] = uu0; u_s[h0+1] = uu1;
        } else {
            const int h0 = t * 2;
            f32x2 ov; ov[0] = c_s[h0]; ov[1] = c_s[h0+1];
            *(f32x2*)(outp + (size_t)blockIdx.x * 1024 + h0) = ov;
        }
        __syncthreads();
    }
}

extern "C" void kernel_launch(void* const* d_in, const int* in_sizes, int n_in,
                              void* d_out, int out_size, void* d_ws, size_t ws_size,
                              hipStream_t stream)
{
    const float* enc = (const float*)d_in[0];   // [256,64,1024] fp32
    const float* W   = (const float*)d_in[1];   // [1024,1024]   fp32
    float* outp = (float*)d_out;                // [256,1024]    fp32
    (void)in_sizes; (void)n_in; (void)out_size;

    // ws layout (11.5 MB)
    char* ws = (char*)d_ws;
    float*  b     = (float*) (ws + 0x000000);  //  64 KB [256,64]
    __bf16* s_hi  = (__bf16*)(ws + 0x080000);  // 512 KB [256,1024]
    __bf16* s_lo  = (__bf16*)(ws + 0x100000);  // 512 KB
    float*  y0    = (float*) (ws + 0x180000);  //   1 MB (y / chat, split-K lo)
    float*  y1    = (float*) (ws + 0x280000);  //   1 MB (y / chat, split-K hi)
    __bf16* Wx_hi = (__bf16*)(ws + 0x380000);  //   2 MB  Wt then Wb (reuse)
    __bf16* Wx_lo = (__bf16*)(ws + 0x580000);  //   2 MB
    __bf16* Q_hi  = (__bf16*)(ws + 0x780000);  //   2 MB [1024,1024]
    __bf16* Q_lo  = (__bf16*)(ws + 0x980000);  //   2 MB

    if (ws_size < 0xB80000) {
        fallback_kernel<<<256, 512, 0, stream>>>(enc, W, outp);
        return;
    }

    // D1: W -> Wt split-bf16 (transposed layout, feeds Q-GEMM)
    convert_wt_kernel<<<dim3(16, 16), 256, 0, stream>>>(W, Wx_hi, Wx_lo);

    // D2: routing iter0 (s = mean_k enc) || Q = Wt Wt^T (LDS-staged)
    routing_q_kernel<0, 1><<<320, 1024, 0, stream>>>(
        enc, y0, y1, b, s_hi, s_lo, Wx_hi, Wx_lo, Q_hi, Q_lo);

    // D3: y = Q s  || convert W -> Wb into the (now dead) Wt buffer
    gemm_split_kernel<1><<<768, 256, 0, stream>>>(
        s_hi, s_lo, Q_hi, Q_lo, y0, y1, W, Wx_hi, Wx_lo);

    // D4: routing iter1 (norm = s.y, scale; b = scale*(E.y); new s)
    routing_q_kernel<1, 0><<<256, 1024, 0, stream>>>(
        enc, y0, y1, b, s_hi, s_lo, Wx_hi, Wx_lo, Q_hi, Q_lo);

    // D5: y = Q s
    gemm_split_kernel<0><<<512, 256, 0, stream>>>(
        s_hi, s_lo, Q_hi, Q_lo, y0, y1, nullptr, nullptr, nullptr);

    // D6: routing iter2 (b += scale*(E.y); final s)
    routing_q_kernel<2, 0><<<256, 1024, 0, stream>>>(
        enc, y0, y1, b, s_hi, s_lo, Wx_hi, Wx_lo, Q_hi, Q_lo);

    // D7: chat = W s   (B = Wb, now in Wx)
    gemm_split_kernel<0><<<512, 256, 0, stream>>>(
        s_hi, s_lo, Wx_hi, Wx_lo, y0, y1, nullptr, nullptr, nullptr);

    // D8: out = squash(chat)
    squash_out_kernel<<<256, 256, 0, stream>>>(y0, y1, outp);
}

// Round 3
// 219.132 us; speedup vs baseline: 1.3229x; 1.1288x over previous
//
#include <hip/hip_runtime.h>

// InductionNetwork capsule routing, C=256, K=64, H=1024, 3 iterations.
// R10: same 8-dispatch Q = W^T W pipeline as R9, but the Q-GEMM is
// re-sharded for parallelism. R9 post-mortem: 64 Q-blocks (128x128) on
// 2-blocks/CU occupancy left a 50-60us MFMA tail on 64 CUs after the
// 256 routing blocks drained (MfmaUtil 2.6%, VALUBusy 2.2%).
// R10 Q-GEMM: 256 blocks x 64x64 tile, 16 waves each (one 16x16 frag
// per wave, full K=1024), BK=64 LDS staging with XOR swizzle. Q work
// now spreads over all CUs and overlaps routing's VALU/HBM work.
// Dispatches:
//   D1 convert_wt             W -> Wt split-bf16 (transposed)
//   D2 routing0 || gemm_Q     enc -> s ; Q = Wt Wt^T (256 x 64x64 tiles)
//   D3 gemm_y || conv_Wb      y = Q s ; W -> Wb split (Wt buffer reused)
//   D4 routing1               norm=s.y, scale, b = scale*(E.y); s
//   D5 gemm_y                 y = Q s
//   D6 routing2               b += scale*(E.y); s
//   D7 gemm_chat              chat = W s  (B = Wb)
//   D8 squash_out             out = squash(chat)
// Split-bf16 operands (verified R6-R9, absmax 4.88e-4):
//   D = Ah.Bh + Ah.Bl + Al.Bh with hi=bf16(x), lo=bf16(x-hi).
// Fragment layout verified R4/R6/R7: A[m=lane&15][k=(lane>>4)*8+j];
// C/D col=lane&15, row=(lane>>4)*4+reg.
// Fallback: R3's proven monolithic kernel if ws too small.

using f32x4  = __attribute__((ext_vector_type(4))) float;
using f32x2  = __attribute__((ext_vector_type(2))) float;
using bf16x8 = __attribute__((ext_vector_type(8))) __bf16;
using bf16x4 = __attribute__((ext_vector_type(4))) __bf16;

struct BfPair { __bf16 hi, lo; };
__device__ inline BfPair split_bf16(float x) {
    BfPair p;
    p.hi = (__bf16)x;
    p.lo = (__bf16)(x - (float)p.hi);
    return p;
}

// ---------------- routing body: prologue + b-update + softmax + wsum -------
// One block per capsule, 1024 threads = 16 waves. Wave w owns enc rows
// w*4..w*4+3; lane holds 16 floats/row. MODE 0: d uniform (iter 0).
// MODE 1: b = scale*(E.y) (store). MODE 2: b += scale*(E.y).
// Prologue (MODE>0): norm = sum(s*y) -> scale; y staged to LDS as u.
template <int MODE>
__device__ __forceinline__ void routing_body(
    const float* __restrict__ enc, const float* __restrict__ y0,
    const float* __restrict__ y1, float* __restrict__ bglob,
    __bf16* __restrict__ s_hi, __bf16* __restrict__ s_lo,
    float (*spart)[1024], float* u_s, float* b_s, float* d_s,
    float* red_s, float* scale_s)
{
    const int t = threadIdx.x, lane = t & 63, w = t >> 6;   // 16 waves
    const int c = blockIdx.x;
    const float* E = enc + (size_t)c * 65536;

    // small prologue loads first so their waitcnt doesn't drain er loads
    float yv = 0.f, sv = 0.f;
    if (MODE > 0) {
        const size_t o = (size_t)c * 1024 + t;
        yv = y0[o] + y1[o];                       // y = Q s (full K)
        sv = (float)s_hi[o] + (float)s_lo[o];     // s as the gemm saw it
    }

    f32x4 er[4][4];                     // 64 VGPRs of enc
    #pragma unroll
    for (int r = 0; r < 4; ++r) {
        const float* ek = E + (size_t)(w * 4 + r) * 1024 + lane * 8;
        er[r][0] = *(const f32x4*)(ek);
        er[r][1] = *(const f32x4*)(ek + 4);
        er[r][2] = *(const f32x4*)(ek + 512);
        er[r][3] = *(const f32x4*)(ek + 516);
    }

    if (MODE > 0) {
        u_s[t] = yv;
        float p = yv * sv;                        // norm = s^T Q s = |W s|^2
        #pragma unroll
        for (int off = 32; off; off >>= 1) p += __shfl_xor(p, off, 64);
        if (lane == 0) red_s[w] = p;
        __syncthreads();
        if (t == 0) {
            float n = 0.f;
            #pragma unroll
            for (int i = 0; i < 16; ++i) n += red_s[i];
            *scale_s = n / ((1.f + n) * sqrtf(n) + 1e-30f);
        }
        __syncthreads();
        const float scale = *scale_s;
        f32x4 uf[4];
        uf[0] = *(const f32x4*)&u_s[lane * 8];
        uf[1] = *(const f32x4*)&u_s[lane * 8 + 4];
        uf[2] = *(const f32x4*)&u_s[512 + lane * 8];
        uf[3] = *(const f32x4*)&u_s[512 + lane * 8 + 4];
        #pragma unroll
        for (int r = 0; r < 4; ++r) {
            float sum = 0.f;
            #pragma unroll
            for (int q = 0; q < 4; ++q)
                #pragma unroll
                for (int j = 0; j < 4; ++j)
                    sum += er[r][q][j] * uf[q][j];
            #pragma unroll
            for (int off = 32; off; off >>= 1) sum += __shfl_xor(sum, off, 64);
            if (lane == 0) {
                const int k = w * 4 + r;
                const float bv =
                    (MODE == 2 ? bglob[c * 64 + k] : 0.f) + scale * sum;
                bglob[c * 64 + k] = bv;     // persist for next iteration
                b_s[k] = bv;
            }
        }
    }
    __syncthreads();

    if (MODE == 0) {
        if (t < 64) d_s[t] = 1.f / 64.f;
    } else if (t < 64) {
        float bv = b_s[t], m = bv;
        #pragma unroll
        for (int off = 32; off; off >>= 1) m = fmaxf(m, __shfl_xor(m, off, 64));
        const float e = expf(bv - m);
        float sm = e;
        #pragma unroll
        for (int off = 32; off; off >>= 1) sm += __shfl_xor(sm, off, 64);
        d_s[t] = e / sm;
    }
    __syncthreads();

    // per-wave partial s from registers (4 rows each)
    #pragma unroll
    for (int q = 0; q < 4; ++q) {
        f32x4 p = {};
        #pragma unroll
        for (int r = 0; r < 4; ++r) {
            const float dk = d_s[w * 4 + r];
            #pragma unroll
            for (int j = 0; j < 4; ++j) p[j] += dk * er[r][q][j];
        }
        const int h = (q >> 1) * 512 + lane * 8 + (q & 1) * 4;
        *(f32x4*)&spart[w][h] = p;
    }
    __syncthreads();

    // cross-wave reduce: 1 h-element per thread; emit split-bf16 s
    {
        float a = 0.f;
        #pragma unroll
        for (int wv = 0; wv < 16; ++wv) a += spart[wv][t];
        const BfPair p = split_bf16(a);
        s_hi[(size_t)c * 1024 + t] = p.hi;
        s_lo[(size_t)c * 1024 + t] = p.lo;
    }
}

// ---- Q = Wt Wt^T (= W^T W): 256 blocks, 64x64 tile each, 16 waves in a
// 4x4 grid (one 16x16 frag per wave), full K=1024, BK=64 LDS staging
// (Ah/Al/Bh/Bl 8 KB each), XOR-swizzled 128-B rows. Epilogue writes
// split-bf16 Q directly.
struct QSmem {
    __bf16 a_hi[64 * 64];
    __bf16 a_lo[64 * 64];
    __bf16 b_hi[64 * 64];
    __bf16 b_lo[64 * 64];
};

__device__ __forceinline__ int swz128(int row, int colbyte) {
    // 128-byte rows; XOR bits 4-6 of the byte offset with row&7
    return row * 128 + (colbyte ^ ((row & 7) << 4));
}

__device__ __forceinline__ void gemm_q_body(
    const __bf16* __restrict__ Wt_hi, const __bf16* __restrict__ Wt_lo,
    __bf16* __restrict__ Q_hi, __bf16* __restrict__ Q_lo, QSmem* sm, int qb)
{
    const int ti = qb >> 4, tj = qb & 15;       // 16x16 grid of 64x64 tiles
    const int t = threadIdx.x;
    const int lane = t & 63, w = t >> 6;
    const int wr = w >> 2, wc = w & 3;          // wave's 16x16 frag
    // staging: threads [0,512) load A rows, [512,1024) load B rows;
    // each thread one 16B chunk of hi and of lo per K-step.
    const int half = t >> 9;
    const int sr   = (t & 511) >> 3;            // row 0..63
    const int scb  = (t & 7) * 16;              // col byte 0..112
    const size_t g = (size_t)((half ? tj : ti) * 64 + sr) * 1024 + scb / 2;
    char* const p_hi = (char*)(half ? sm->b_hi : sm->a_hi) + swz128(sr, scb);
    char* const p_lo = (char*)(half ? sm->b_lo : sm->a_lo) + swz128(sr, scb);

    f32x4 acc = {};
    for (int k0 = 0; k0 < 1024; k0 += 64) {
        if (k0) __syncthreads();                // prev step's reads done
        *(bf16x8*)p_hi = *(const bf16x8*)(Wt_hi + g + k0);
        *(bf16x8*)p_lo = *(const bf16x8*)(Wt_lo + g + k0);
        __syncthreads();
        #pragma unroll
        for (int kk = 0; kk < 2; ++kk) {
            const int cb = kk * 64 + (lane >> 4) * 16;  // col byte of frag
            const int m = wr * 16 + (lane & 15);
            const int n = wc * 16 + (lane & 15);
            const bf16x8 ah = *(const bf16x8*)((char*)sm->a_hi + swz128(m, cb));
            const bf16x8 al = *(const bf16x8*)((char*)sm->a_lo + swz128(m, cb));
            const bf16x8 bh = *(const bf16x8*)((char*)sm->b_hi + swz128(n, cb));
            const bf16x8 bl = *(const bf16x8*)((char*)sm->b_lo + swz128(n, cb));
            acc = __builtin_amdgcn_mfma_f32_16x16x32_bf16(ah, bh, acc, 0, 0, 0);
            acc = __builtin_amdgcn_mfma_f32_16x16x32_bf16(ah, bl, acc, 0, 0, 0);
            acc = __builtin_amdgcn_mfma_f32_16x16x32_bf16(al, bh, acc, 0, 0, 0);
        }
    }
    const int rr = (lane >> 4) * 4, colb = lane & 15;
    #pragma unroll
    for (int r = 0; r < 4; ++r) {
        const BfPair p = split_bf16(acc[r]);
        const size_t idx =
            (size_t)(ti * 64 + wr * 16 + rr + r) * 1024 +
            tj * 64 + wc * 16 + colb;
        Q_hi[idx] = p.hi;
        Q_lo[idx] = p.lo;
    }
}

// Merged dispatch: blocks [0,256) = routing capsule c; with WITH_Q, blocks
// [256,512) run gemm_Q (one 64x64 tile per block).
template <int MODE, int WITH_Q>
__global__ __launch_bounds__(1024) void routing_q_kernel(
    const float* __restrict__ enc, const float* __restrict__ y0,
    const float* __restrict__ y1, float* __restrict__ bglob,
    __bf16* __restrict__ s_hi, __bf16* __restrict__ s_lo,
    const __bf16* __restrict__ Wt_hi, const __bf16* __restrict__ Wt_lo,
    __bf16* __restrict__ Q_hi, __bf16* __restrict__ Q_lo)
{
    __shared__ union SM {
        struct {
            float spart[16][1024];  // 64 KB: per-wave partial s
            float u_s[1024];        //  4 KB: y staged for the dots
            float b_s[64], d_s[64], red_s[16], scale_s;
        } r;
        QSmem q;                    // 32 KB: Q staging tiles
    } sm;

    if (WITH_Q && blockIdx.x >= 256) {
        gemm_q_body(Wt_hi, Wt_lo, Q_hi, Q_lo, &sm.q, blockIdx.x - 256);
        return;
    }
    routing_body<MODE>(enc, y0, y1, bglob, s_hi, s_lo,
                       sm.r.spart, sm.r.u_s, sm.r.b_s, sm.r.d_s,
                       sm.r.red_s, &sm.r.scale_s);
}

// ---- split-bf16 NT GEMM, split-K x2: 2048 waves as 512 blocks x 4 waves.
// Wave gw: task=gw>>1 (mt=task>>6, nt=task&63), K-half kh=gw&1.
// With CONV, blocks [512,768) convert W fp32 -> split-bf16 Wd (coalesced).
template <int CONV>
__global__ __launch_bounds__(256) void gemm_split_kernel(
    const __bf16* __restrict__ Ah, const __bf16* __restrict__ Al,
    const __bf16* __restrict__ Bh, const __bf16* __restrict__ Bl,
    float* __restrict__ C0, float* __restrict__ C1,
    const float* __restrict__ Wsrc, __bf16* __restrict__ Wd_hi,
    __bf16* __restrict__ Wd_lo)
{
    if (CONV && blockIdx.x >= 512) {
        const int b = blockIdx.x - 512;             // 0..255
        const size_t base = (size_t)b * 4096 + (threadIdx.x << 2);
        #pragma unroll
        for (int q = 0; q < 4; ++q) {
            const size_t idx = base + (size_t)q * 1024;
            const f32x4 v = *(const f32x4*)(Wsrc + idx);
            bf16x4 hv, lv;
            #pragma unroll
            for (int j = 0; j < 4; ++j) {
                const BfPair p = split_bf16(v[j]);
                hv[j] = p.hi;
                lv[j] = p.lo;
            }
            *(bf16x4*)(Wd_hi + idx) = hv;
            *(bf16x4*)(Wd_lo + idx) = lv;
        }
        return;
    }

    const int w = threadIdx.x >> 6;
    const int gw = blockIdx.x * 4 + w;
    const int task = gw >> 1;
    const int kh   = gw & 1;
    const int mt   = task >> 6;
    const int nt   = task & 63;
    const int lane = threadIdx.x & 63;
    const int kq   = (lane >> 4) * 8 + kh * 512;
    const size_t aoff = (size_t)(mt * 16 + (lane & 15)) * 1024 + kq;
    const size_t boff = (size_t)(nt * 16 + (lane & 15)) * 1024 + kq;

    f32x4 hh = {}, hl = {}, lh = {};
    #pragma unroll 4
    for (int k0 = 0; k0 < 512; k0 += 32) {
        bf16x8 ah = *(const bf16x8*)(Ah + aoff + k0);
        bf16x8 al = *(const bf16x8*)(Al + aoff + k0);
        bf16x8 bh = *(const bf16x8*)(Bh + boff + k0);
        bf16x8 bl = *(const bf16x8*)(Bl + boff + k0);
        hh = __builtin_amdgcn_mfma_f32_16x16x32_bf16(ah, bh, hh, 0, 0, 0);
        hl = __builtin_amdgcn_mfma_f32_16x16x32_bf16(ah, bl, hl, 0, 0, 0);
        lh = __builtin_amdgcn_mfma_f32_16x16x32_bf16(al, bh, lh, 0, 0, 0);
    }
    f32x4 acc = hh + hl + lh;
    float* Cc = kh ? C1 : C0;
    const int rr = (lane >> 4) * 4, colb = lane & 15;
    #pragma unroll
    for (int r = 0; r < 4; ++r)
        Cc[(size_t)(mt * 16 + rr + r) * 1024 + nt * 16 + colb] = acc[r];
}

// ---------------- final squash: sums split-K chat, emits out ---------------
__global__ __launch_bounds__(256) void squash_out_kernel(
    const float* __restrict__ chat0, const float* __restrict__ chat1,
    float* __restrict__ outp)
{
    __shared__ float wsum[4];
    const int c = blockIdx.x, t = threadIdx.x;
    const int lane = t & 63, w = t >> 6;
    const size_t o = (size_t)c * 1024 + t * 4;
    f32x4 v = *(const f32x4*)(chat0 + o) + *(const f32x4*)(chat1 + o);
    float ss = v[0]*v[0] + v[1]*v[1] + v[2]*v[2] + v[3]*v[3];
    #pragma unroll
    for (int off = 32; off; off >>= 1) ss += __shfl_xor(ss, off, 64);
    if (lane == 0) wsum[w] = ss;
    __syncthreads();
    const float norm = wsum[0] + wsum[1] + wsum[2] + wsum[3];
    const float scale = norm / ((1.f + norm) * sqrtf(norm) + 1e-30f);
    *(f32x4*)(outp + o) = v * scale;
}

// ---------------- W -> split bf16 transposed (for Q-GEMM) ------------------
__global__ __launch_bounds__(256) void convert_wt_kernel(
    const float* __restrict__ W, __bf16* __restrict__ Wt_hi,
    __bf16* __restrict__ Wt_lo)
{
    __shared__ float tile[64][65];
    const int bx = blockIdx.x, by = blockIdx.y;
    const int tx = threadIdx.x & 63, ty = threadIdx.x >> 6;
    for (int i = ty; i < 64; i += 4)
        tile[i][tx] = W[(size_t)(by * 64 + i) * 1024 + bx * 64 + tx];
    __syncthreads();
    for (int i = ty; i < 64; i += 4) {
        const size_t idx = (size_t)(bx * 64 + i) * 1024 + by * 64 + tx;
        const BfPair p = split_bf16(tile[tx][i]);
        Wt_hi[idx] = p.hi;
        Wt_lo[idx] = p.lo;
    }
}

// ---------------- fallback: R3's proven monolithic fp32 kernel --------------
__global__ __launch_bounds__(512) void fallback_kernel(
    const float* __restrict__ enc, const float* __restrict__ W,
    float* __restrict__ outp)
{
    __shared__ float u_s[1024], s_s[1024], c_s[1024], chat_s[1024];
    __shared__ float b_s[64], d_s[64], red_s[8];
    const int t = threadIdx.x, lane = t & 63, w = t >> 6;
    const float* erow = enc + (size_t)blockIdx.x * 65536;

    if (t < 64) b_s[t] = 0.f;
    __syncthreads();

    for (int it = 0; it < 3; ++it) {
        if (it > 0) {
            f32x4 uf[4];
            #pragma unroll
            for (int q = 0; q < 2; ++q) {
                uf[2*q]   = *(const f32x4*)&u_s[q*512 + lane*8];
                uf[2*q+1] = *(const f32x4*)&u_s[q*512 + lane*8 + 4];
            }
            for (int r = 0; r < 8; ++r) {
                const int k = w * 8 + r;
                const float* ek = erow + (size_t)k * 1024;
                float sum = 0.f;
                #pragma unroll
                for (int q = 0; q < 2; ++q) {
                    f32x4 e0 = *(const f32x4*)(ek + q*512 + lane*8);
                    f32x4 e1 = *(const f32x4*)(ek + q*512 + lane*8 + 4);
                    #pragma unroll
                    for (int j = 0; j < 4; ++j) {
                        sum += e0[j] * uf[2*q][j];
                        sum += e1[j] * uf[2*q+1][j];
                    }
                }
                #pragma unroll
                for (int off = 32; off; off >>= 1) sum += __shfl_xor(sum, off, 64);
                if (lane == 0) b_s[k] += sum;
            }
            __syncthreads();
        }
        if (t < 64) {
            float bv = b_s[t], m = bv;
            #pragma unroll
            for (int off = 32; off; off >>= 1) m = fmaxf(m, __shfl_xor(m, off, 64));
            float e = expf(bv - m), sm = e;
            #pragma unroll
            for (int off = 32; off; off >>= 1) sm += __shfl_xor(sm, off, 64);
            d_s[t] = e / sm;
        }
        __syncthreads();
        {
            const int h0 = t * 2;
            float a0 = 0.f, a1 = 0.f;
            for (int k = 0; k < 64; ++k) {
                f32x2 ev = *(const f32x2*)(erow + (size_t)k * 1024 + h0);
                a0 += d_s[k] * ev[0]; a1 += d_s[k] * ev[1];
            }
            s_s[h0] = a0; s_s[h0+1] = a1;
        }
        __syncthreads();
        {
            f32x4 sf[4];
            #pragma unroll
            for (int q = 0; q < 2; ++q) {
                sf[2*q]   = *(const f32x4*)&s_s[q*512 + lane*8];
                sf[2*q+1] = *(const f32x4*)&s_s[q*512 + lane*8 + 4];
            }
            for (int r = 0; r < 128; ++r) {
                const int d = w * 128 + r;
                const float* wr = W + (size_t)d * 1024;
                float sum = 0.f;
                #pragma unroll
                for (int q = 0; q < 2; ++q) {
                    f32x4 w0 = *(const f32x4*)(wr + q*512 + lane*8);
                    f32x4 w1 = *(const f32x4*)(wr + q*512 + lane*8 + 4);
                    #pragma unroll
                    for (int j = 0; j < 4; ++j) {
                        sum += w0[j] * sf[2*q][j];
                        sum += w1[j] * sf[2*q+1][j];
                    }
                }
                #pragma unroll
                for (int off = 32; off; off >>= 1) sum += __shfl_xor(sum, off, 64);
                if (lane == 0) chat_s[d] = sum;
            }
        }
        __syncthreads();
        {
            const int h0 = t * 2;
            float v0 = chat_s[h0], v1 = chat_s[h0+1];
            float ss = v0*v0 + v1*v1;
            #pragma unroll
            for (int off = 32; off; off >>= 1) ss += __shfl_xor(ss, off, 64);
            if (lane == 0) red_s[w] = ss;
            __syncthreads();
            float norm = 0.f;
            #pragma unroll
            for (int i = 0; i < 8; ++i) norm += red_s[i];
            const float scale = norm / ((1.f + norm) * sqrtf(norm) + 1e-30f);
            c_s[h0] = v0 * scale; c_s[h0+1] = v1 * scale;
        }
        __syncthreads();
        if (it < 2) {
            const int h0 = t * 2;
            float uu0 = 0.f, uu1 = 0.f;
            for (int d = 0; d < 1024; ++d) {
                f32x2 wv = *(const f32x2*)(W + (size_t)d * 1024 + h0);
                uu0 += c_s[d] * wv[0]; uu1 += c_s[d] * wv[1];
            }
            u_s[h0] = uu0; u_s[h0+1] = uu1;
        } else {
            const int h0 = t * 2;
            f32x2 ov; ov[0] = c_s[h0]; ov[1] = c_s[h0+1];
            *(f32x2*)(outp + (size_t)blockIdx.x * 1024 + h0) = ov;
        }
        __syncthreads();
    }
}

extern "C" void kernel_launch(void* const* d_in, const int* in_sizes, int n_in,
                              void* d_out, int out_size, void* d_ws, size_t ws_size,
                              hipStream_t stream)
{
    const float* enc = (const float*)d_in[0];   // [256,64,1024] fp32
    const float* W   = (const float*)d_in[1];   // [1024,1024]   fp32
    float* outp = (float*)d_out;                // [256,1024]    fp32
    (void)in_sizes; (void)n_in; (void)out_size;

    // ws layout (11.5 MB)
    char* ws = (char*)d_ws;
    float*  b     = (float*) (ws + 0x000000);  //  64 KB [256,64]
    __bf16* s_hi  = (__bf16*)(ws + 0x080000);  // 512 KB [256,1024]
    __bf16* s_lo  = (__bf16*)(ws + 0x100000);  // 512 KB
    float*  y0    = (float*) (ws + 0x180000);  //   1 MB (y / chat, split-K lo)
    float*  y1    = (float*) (ws + 0x280000);  //   1 MB (y / chat, split-K hi)
    __bf16* Wx_hi = (__bf16*)(ws + 0x380000);  //   2 MB  Wt then Wb (reuse)
    __bf16* Wx_lo = (__bf16*)(ws + 0x580000);  //   2 MB
    __bf16* Q_hi  = (__bf16*)(ws + 0x780000);  //   2 MB [1024,1024]
    __bf16* Q_lo  = (__bf16*)(ws + 0x980000);  //   2 MB

    if (ws_size < 0xB80000) {
        fallback_kernel<<<256, 512, 0, stream>>>(enc, W, outp);
        return;
    }

    // D1: W -> Wt split-bf16 (transposed layout, feeds Q-GEMM)
    convert_wt_kernel<<<dim3(16, 16), 256, 0, stream>>>(W, Wx_hi, Wx_lo);

    // D2: routing iter0 (s = mean_k enc) || Q = Wt Wt^T (256 x 64x64)
    routing_q_kernel<0, 1><<<512, 1024, 0, stream>>>(
        enc, y0, y1, b, s_hi, s_lo, Wx_hi, Wx_lo, Q_hi, Q_lo);

    // D3: y = Q s  || convert W -> Wb into the (now dead) Wt buffer
    gemm_split_kernel<1><<<768, 256, 0, stream>>>(
        s_hi, s_lo, Q_hi, Q_lo, y0, y1, W, Wx_hi, Wx_lo);

    // D4: routing iter1 (norm = s.y, scale; b = scale*(E.y); new s)
    routing_q_kernel<1, 0><<<256, 1024, 0, stream>>>(
        enc, y0, y1, b, s_hi, s_lo, Wx_hi, Wx_lo, Q_hi, Q_lo);

    // D5: y = Q s
    gemm_split_kernel<0><<<512, 256, 0, stream>>>(
        s_hi, s_lo, Q_hi, Q_lo, y0, y1, nullptr, nullptr, nullptr);

    // D6: routing iter2 (b += scale*(E.y); final s)
    routing_q_kernel<2, 0><<<256, 1024, 0, stream>>>(
        enc, y0, y1, b, s_hi, s_lo, Wx_hi, Wx_lo, Q_hi, Q_lo);

    // D7: chat = W s   (B = Wb, now in Wx)
    gemm_split_kernel<0><<<512, 256, 0, stream>>>(
        s_hi, s_lo, Wx_hi, Wx_lo, y0, y1, nullptr, nullptr, nullptr);

    // D8: out = squash(chat)
    squash_out_kernel<<<256, 256, 0, stream>>>(y0, y1, outp);
}

// Round 4
// 199.223 us; speedup vs baseline: 1.4551x; 1.0999x over previous
//
#include <hip/hip_runtime.h>

// InductionNetwork capsule routing, C=256, K=64, H=1024, 3 iterations.
// R11: R10 post-mortem found VGPR_Count=36 on the routing kernel: the
// compiler was targeting 2 blocks/CU (<=64 VGPR) and rematerializing the
// 64-VGPR enc tile instead of keeping it resident -> routing dispatches
// ran latency-bound at ~1 TB/s instead of BW-bound. R11:
//   - routing: __launch_bounds__(1024, 4) (VGPR cap 128, 1 block/CU) +
//     inline-asm register pin on er[][] so enc is loaded ONCE and held.
//   - Q-GEMM un-merged from routing0 into its own dispatch (256 blocks
//     x 256 thr, 4 waves, 2x2 frags/wave, 32 KB LDS, XOR swizzle) for
//     counter attribution and better occupancy (5 blocks/CU).
// Dispatches (9):
//   D1 convert_wt   W -> Wt split-bf16 (transposed)
//   D2 gemm_Q       Q = Wt Wt^T
//   D3 routing0     s = mean_k enc
//   D4 gemm_y||convWb   y = Q s ; W -> Wb split (Wt buffer reused)
//   D5 routing1     norm=s.y -> scale; b = scale*(E.y); s
//   D6 gemm_y       y = Q s
//   D7 routing2     b += scale*(E.y); s
//   D8 gemm_chat    chat = W s  (B = Wb)
//   D9 squash_out   out = squash(chat)
// Split-bf16 operands (verified R6-R10, absmax 4.88e-4):
//   D = Ah.Bh + Ah.Bl + Al.Bh with hi=bf16(x), lo=bf16(x-hi).
// Fragment layout verified R4/R6/R7: A[m=lane&15][k=(lane>>4)*8+j];
// C/D col=lane&15, row=(lane>>4)*4+reg.
// Fallback: R3's proven monolithic kernel if ws too small.

using f32x4  = __attribute__((ext_vector_type(4))) float;
using f32x2  = __attribute__((ext_vector_type(2))) float;
using bf16x8 = __attribute__((ext_vector_type(8))) __bf16;
using bf16x4 = __attribute__((ext_vector_type(4))) __bf16;

struct BfPair { __bf16 hi, lo; };
__device__ inline BfPair split_bf16(float x) {
    BfPair p;
    p.hi = (__bf16)x;
    p.lo = (__bf16)(x - (float)p.hi);
    return p;
}

// ---------------- routing: prologue + b-update + softmax + weighted sum ----
// One block per capsule, 1024 threads = 16 waves, 1 block/CU. Wave w owns
// enc rows w*4..w*4+3; lane holds 16 floats/row (64 VGPRs, pinned).
// MODE 0: d uniform (iter 0). MODE 1: b = scale*(E.y). MODE 2: b += ...
template <int MODE>
__global__ __launch_bounds__(1024, 4) void routing_kernel(
    const float* __restrict__ enc, const float* __restrict__ y0,
    const float* __restrict__ y1, float* __restrict__ bglob,
    __bf16* __restrict__ s_hi, __bf16* __restrict__ s_lo)
{
    __shared__ float spart[16][1024];   // 64 KB: per-wave partial s
    __shared__ float u_s[1024];         //  4 KB: y staged for the dots
    __shared__ float b_s[64], d_s[64], red_s[16], scale_s;

    const int t = threadIdx.x, lane = t & 63, w = t >> 6;   // 16 waves
    const int c = blockIdx.x;
    const float* E = enc + (size_t)c * 65536;

    // small prologue loads first so their waitcnt doesn't drain er loads
    float yv = 0.f, sv = 0.f;
    if (MODE > 0) {
        const size_t o = (size_t)c * 1024 + t;
        yv = y0[o] + y1[o];                       // y = Q s (full K)
        sv = (float)s_hi[o] + (float)s_lo[o];     // s as the gemm saw it
    }

    f32x4 er[4][4];                     // 64 VGPRs of enc
    #pragma unroll
    for (int r = 0; r < 4; ++r) {
        const float* ek = E + (size_t)(w * 4 + r) * 1024 + lane * 8;
        er[r][0] = *(const f32x4*)(ek);
        er[r][1] = *(const f32x4*)(ek + 4);
        er[r][2] = *(const f32x4*)(ek + 512);
        er[r][3] = *(const f32x4*)(ek + 516);
    }
    // Pin er in VGPRs: opaque defs the compiler cannot rematerialize by
    // re-loading from global after the barrier (R10: VGPR_Count=36 showed
    // the enc tile was never actually register-resident).
    #pragma unroll
    for (int r = 0; r < 4; ++r)
        #pragma unroll
        for (int q = 0; q < 4; ++q)
            asm volatile("" : "+v"(er[r][q]));

    if (MODE > 0) {
        u_s[t] = yv;
        float p = yv * sv;                        // norm = s^T Q s = |W s|^2
        #pragma unroll
        for (int off = 32; off; off >>= 1) p += __shfl_xor(p, off, 64);
        if (lane == 0) red_s[w] = p;
        __syncthreads();
        if (t == 0) {
            float n = 0.f;
            #pragma unroll
            for (int i = 0; i < 16; ++i) n += red_s[i];
            scale_s = n / ((1.f + n) * sqrtf(n) + 1e-30f);
        }
        __syncthreads();
        const float scale = scale_s;
        f32x4 uf[4];
        uf[0] = *(const f32x4*)&u_s[lane * 8];
        uf[1] = *(const f32x4*)&u_s[lane * 8 + 4];
        uf[2] = *(const f32x4*)&u_s[512 + lane * 8];
        uf[3] = *(const f32x4*)&u_s[512 + lane * 8 + 4];
        #pragma unroll
        for (int r = 0; r < 4; ++r) {
            float sum = 0.f;
            #pragma unroll
            for (int q = 0; q < 4; ++q)
                #pragma unroll
                for (int j = 0; j < 4; ++j)
                    sum += er[r][q][j] * uf[q][j];
            #pragma unroll
            for (int off = 32; off; off >>= 1) sum += __shfl_xor(sum, off, 64);
            if (lane == 0) {
                const int k = w * 4 + r;
                const float bv =
                    (MODE == 2 ? bglob[c * 64 + k] : 0.f) + scale * sum;
                bglob[c * 64 + k] = bv;     // persist for next iteration
                b_s[k] = bv;
            }
        }
    }
    __syncthreads();

    if (MODE == 0) {
        if (t < 64) d_s[t] = 1.f / 64.f;
    } else if (t < 64) {
        float bv = b_s[t], m = bv;
        #pragma unroll
        for (int off = 32; off; off >>= 1) m = fmaxf(m, __shfl_xor(m, off, 64));
        const float e = expf(bv - m);
        float sm = e;
        #pragma unroll
        for (int off = 32; off; off >>= 1) sm += __shfl_xor(sm, off, 64);
        d_s[t] = e / sm;
    }
    __syncthreads();

    // per-wave partial s from registers (4 rows each)
    #pragma unroll
    for (int q = 0; q < 4; ++q) {
        f32x4 p = {};
        #pragma unroll
        for (int r = 0; r < 4; ++r) {
            const float dk = d_s[w * 4 + r];
            #pragma unroll
            for (int j = 0; j < 4; ++j) p[j] += dk * er[r][q][j];
        }
        const int h = (q >> 1) * 512 + lane * 8 + (q & 1) * 4;
        *(f32x4*)&spart[w][h] = p;
    }
    __syncthreads();

    // cross-wave reduce: 1 h-element per thread; emit split-bf16 s
    {
        float a = 0.f;
        #pragma unroll
        for (int wv = 0; wv < 16; ++wv) a += spart[wv][t];
        const BfPair p = split_bf16(a);
        s_hi[(size_t)c * 1024 + t] = p.hi;
        s_lo[(size_t)c * 1024 + t] = p.lo;
    }
}

// ---- Q = Wt Wt^T (= W^T W): standalone. 256 blocks (16x16 tile grid),
// 256 threads = 4 waves in a 2x2 grid, each wave a 32x32 sub-tile
// (2x2 16x16 frags), BK=64 LDS staging (4 x 8 KB, XOR-swizzled rows).
// Epilogue writes split-bf16 Q directly.
struct QSmem {
    __bf16 a_hi[64 * 64];
    __bf16 a_lo[64 * 64];
    __bf16 b_hi[64 * 64];
    __bf16 b_lo[64 * 64];
};

__device__ __forceinline__ int swz128(int row, int colbyte) {
    // 128-byte rows; XOR bits 4-6 of the byte offset with row&7
    return row * 128 + (colbyte ^ ((row & 7) << 4));
}

__global__ __launch_bounds__(256) void gemm_q_kernel(
    const __bf16* __restrict__ Wt_hi, const __bf16* __restrict__ Wt_lo,
    __bf16* __restrict__ Q_hi, __bf16* __restrict__ Q_lo)
{
    __shared__ QSmem sm;
    const int qb = blockIdx.x;
    const int ti = qb >> 4, tj = qb & 15;       // 16x16 grid of 64x64 tiles
    const int t = threadIdx.x;
    const int lane = t & 63, w = t >> 6;        // 4 waves
    const int wr = w >> 1, wc = w & 1;          // wave's 32x32 sub-tile
    // staging: thread loads 2 x 16B per matrix-half per K-step
    const int sr  = t >> 2;                     // row 0..63
    const int scb = (t & 3) * 16;               // col byte {0,16,32,48}
    const size_t ga = (size_t)(ti * 64 + sr) * 1024 + scb / 2;
    const size_t gb = (size_t)(tj * 64 + sr) * 1024 + scb / 2;

    f32x4 acc[2][2] = {};
    for (int k0 = 0; k0 < 1024; k0 += 64) {
        if (k0) __syncthreads();                // prev step's reads done
        #pragma unroll
        for (int h = 0; h < 2; ++h) {
            const int cb = scb + h * 64;        // covers full 128-B row
            const size_t gao = ga + h * 32 + k0;
            const size_t gbo = gb + h * 32 + k0;
            *(bf16x8*)((char*)sm.a_hi + swz128(sr, cb)) = *(const bf16x8*)(Wt_hi + gao);
            *(bf16x8*)((char*)sm.a_lo + swz128(sr, cb)) = *(const bf16x8*)(Wt_lo + gao);
            *(bf16x8*)((char*)sm.b_hi + swz128(sr, cb)) = *(const bf16x8*)(Wt_hi + gbo);
            *(bf16x8*)((char*)sm.b_lo + swz128(sr, cb)) = *(const bf16x8*)(Wt_lo + gbo);
        }
        __syncthreads();
        #pragma unroll
        for (int kk = 0; kk < 2; ++kk) {
            const int cb = kk * 64 + (lane >> 4) * 16;  // col byte of frag
            bf16x8 ah[2], al[2], bh[2], bl[2];
            #pragma unroll
            for (int mi = 0; mi < 2; ++mi) {
                const int m = wr * 32 + mi * 16 + (lane & 15);
                ah[mi] = *(const bf16x8*)((char*)sm.a_hi + swz128(m, cb));
                al[mi] = *(const bf16x8*)((char*)sm.a_lo + swz128(m, cb));
            }
            #pragma unroll
            for (int ni = 0; ni < 2; ++ni) {
                const int n = wc * 32 + ni * 16 + (lane & 15);
                bh[ni] = *(const bf16x8*)((char*)sm.b_hi + swz128(n, cb));
                bl[ni] = *(const bf16x8*)((char*)sm.b_lo + swz128(n, cb));
            }
            #pragma unroll
            for (int mi = 0; mi < 2; ++mi)
                #pragma unroll
                for (int ni = 0; ni < 2; ++ni) {
                    f32x4 a = acc[mi][ni];
                    a = __builtin_amdgcn_mfma_f32_16x16x32_bf16(ah[mi], bh[ni], a, 0, 0, 0);
                    a = __builtin_amdgcn_mfma_f32_16x16x32_bf16(ah[mi], bl[ni], a, 0, 0, 0);
                    a = __builtin_amdgcn_mfma_f32_16x16x32_bf16(al[mi], bh[ni], a, 0, 0, 0);
                    acc[mi][ni] = a;
                }
        }
    }
    const int rr = (lane >> 4) * 4, colb = lane & 15;
    #pragma unroll
    for (int mi = 0; mi < 2; ++mi)
        #pragma unroll
        for (int ni = 0; ni < 2; ++ni)
            #pragma unroll
            for (int r = 0; r < 4; ++r) {
                const BfPair p = split_bf16(acc[mi][ni][r]);
                const size_t idx =
                    (size_t)(ti * 64 + wr * 32 + mi * 16 + rr + r) * 1024 +
                    tj * 64 + wc * 32 + ni * 16 + colb;
                Q_hi[idx] = p.hi;
                Q_lo[idx] = p.lo;
            }
}

// ---- split-bf16 NT GEMM, split-K x2: 2048 waves as 512 blocks x 4 waves.
// Wave gw: task=gw>>1 (mt=task>>6, nt=task&63), K-half kh=gw&1.
// With CONV, blocks [512,768) convert W fp32 -> split-bf16 Wd (coalesced).
template <int CONV>
__global__ __launch_bounds__(256) void gemm_split_kernel(
    const __bf16* __restrict__ Ah, const __bf16* __restrict__ Al,
    const __bf16* __restrict__ Bh, const __bf16* __restrict__ Bl,
    float* __restrict__ C0, float* __restrict__ C1,
    const float* __restrict__ Wsrc, __bf16* __restrict__ Wd_hi,
    __bf16* __restrict__ Wd_lo)
{
    if (CONV && blockIdx.x >= 512) {
        const int b = blockIdx.x - 512;             // 0..255
        const size_t base = (size_t)b * 4096 + (threadIdx.x << 2);
        #pragma unroll
        for (int q = 0; q < 4; ++q) {
            const size_t idx = base + (size_t)q * 1024;
            const f32x4 v = *(const f32x4*)(Wsrc + idx);
            bf16x4 hv, lv;
            #pragma unroll
            for (int j = 0; j < 4; ++j) {
                const BfPair p = split_bf16(v[j]);
                hv[j] = p.hi;
                lv[j] = p.lo;
            }
            *(bf16x4*)(Wd_hi + idx) = hv;
            *(bf16x4*)(Wd_lo + idx) = lv;
        }
        return;
    }

    const int w = threadIdx.x >> 6;
    const int gw = blockIdx.x * 4 + w;
    const int task = gw >> 1;
    const int kh   = gw & 1;
    const int mt   = task >> 6;
    const int nt   = task & 63;
    const int lane = threadIdx.x & 63;
    const int kq   = (lane >> 4) * 8 + kh * 512;
    const size_t aoff = (size_t)(mt * 16 + (lane & 15)) * 1024 + kq;
    const size_t boff = (size_t)(nt * 16 + (lane & 15)) * 1024 + kq;

    f32x4 hh = {}, hl = {}, lh = {};
    #pragma unroll 4
    for (int k0 = 0; k0 < 512; k0 += 32) {
        bf16x8 ah = *(const bf16x8*)(Ah + aoff + k0);
        bf16x8 al = *(const bf16x8*)(Al + aoff + k0);
        bf16x8 bh = *(const bf16x8*)(Bh + boff + k0);
        bf16x8 bl = *(const bf16x8*)(Bl + boff + k0);
        hh = __builtin_amdgcn_mfma_f32_16x16x32_bf16(ah, bh, hh, 0, 0, 0);
        hl = __builtin_amdgcn_mfma_f32_16x16x32_bf16(ah, bl, hl, 0, 0, 0);
        lh = __builtin_amdgcn_mfma_f32_16x16x32_bf16(al, bh, lh, 0, 0, 0);
    }
    f32x4 acc = hh + hl + lh;
    float* Cc = kh ? C1 : C0;
    const int rr = (lane >> 4) * 4, colb = lane & 15;
    #pragma unroll
    for (int r = 0; r < 4; ++r)
        Cc[(size_t)(mt * 16 + rr + r) * 1024 + nt * 16 + colb] = acc[r];
}

// ---------------- final squash: sums split-K chat, emits out ---------------
__global__ __launch_bounds__(256) void squash_out_kernel(
    const float* __restrict__ chat0, const float* __restrict__ chat1,
    float* __restrict__ outp)
{
    __shared__ float wsum[4];
    const int c = blockIdx.x, t = threadIdx.x;
    const int lane = t & 63, w = t >> 6;
    const size_t o = (size_t)c * 1024 + t * 4;
    f32x4 v = *(const f32x4*)(chat0 + o) + *(const f32x4*)(chat1 + o);
    float ss = v[0]*v[0] + v[1]*v[1] + v[2]*v[2] + v[3]*v[3];
    #pragma unroll
    for (int off = 32; off; off >>= 1) ss += __shfl_xor(ss, off, 64);
    if (lane == 0) wsum[w] = ss;
    __syncthreads();
    const float norm = wsum[0] + wsum[1] + wsum[2] + wsum[3];
    const float scale = norm / ((1.f + norm) * sqrtf(norm) + 1e-30f);
    *(f32x4*)(outp + o) = v * scale;
}

// ---------------- W -> split bf16 transposed (for Q-GEMM) ------------------
__global__ __launch_bounds__(256) void convert_wt_kernel(
    const float* __restrict__ W, __bf16* __restrict__ Wt_hi,
    __bf16* __restrict__ Wt_lo)
{
    __shared__ float tile[64][65];
    const int bx = blockIdx.x, by = blockIdx.y;
    const int tx = threadIdx.x & 63, ty = threadIdx.x >> 6;
    for (int i = ty; i < 64; i += 4)
        tile[i][tx] = W[(size_t)(by * 64 + i) * 1024 + bx * 64 + tx];
    __syncthreads();
    for (int i = ty; i < 64; i += 4) {
        const size_t idx = (size_t)(bx * 64 + i) * 1024 + by * 64 + tx;
        const BfPair p = split_bf16(tile[tx][i]);
        Wt_hi[idx] = p.hi;
        Wt_lo[idx] = p.lo;
    }
}

// ---------------- fallback: R3's proven monolithic fp32 kernel --------------
__global__ __launch_bounds__(512) void fallback_kernel(
    const float* __restrict__ enc, const float* __restrict__ W,
    float* __restrict__ outp)
{
    __shared__ float u_s[1024], s_s[1024], c_s[1024], chat_s[1024];
    __shared__ float b_s[64], d_s[64], red_s[8];
    const int t = threadIdx.x, lane = t & 63, w = t >> 6;
    const float* erow = enc + (size_t)blockIdx.x * 65536;

    if (t < 64) b_s[t] = 0.f;
    __syncthreads();

    for (int it = 0; it < 3; ++it) {
        if (it > 0) {
            f32x4 uf[4];
            #pragma unroll
            for (int q = 0; q < 2; ++q) {
                uf[2*q]   = *(const f32x4*)&u_s[q*512 + lane*8];
                uf[2*q+1] = *(const f32x4*)&u_s[q*512 + lane*8 + 4];
            }
            for (int r = 0; r < 8; ++r) {
                const int k = w * 8 + r;
                const float* ek = erow + (size_t)k * 1024;
                float sum = 0.f;
                #pragma unroll
                for (int q = 0; q < 2; ++q) {
                    f32x4 e0 = *(const f32x4*)(ek + q*512 + lane*8);
                    f32x4 e1 = *(const f32x4*)(ek + q*512 + lane*8 + 4);
                    #pragma unroll
                    for (int j = 0; j < 4; ++j) {
                        sum += e0[j] * uf[2*q][j];
                        sum += e1[j] * uf[2*q+1][j];
                    }
                }
                #pragma unroll
                for (int off = 32; off; off >>= 1) sum += __shfl_xor(sum, off, 64);
                if (lane == 0) b_s[k] += sum;
            }
            __syncthreads();
        }
        if (t < 64) {
            float bv = b_s[t], m = bv;
            #pragma unroll
            for (int off = 32; off; off >>= 1) m = fmaxf(m, __shfl_xor(m, off, 64));
            float e = expf(bv - m), sm = e;
            #pragma unroll
            for (int off = 32; off; off >>= 1) sm += __shfl_xor(sm, off, 64);
            d_s[t] = e / sm;
        }
        __syncthreads();
        {
            const int h0 = t * 2;
            float a0 = 0.f, a1 = 0.f;
            for (int k = 0; k < 64; ++k) {
                f32x2 ev = *(const f32x2*)(erow + (size_t)k * 1024 + h0);
                a0 += d_s[k] * ev[0]; a1 += d_s[k] * ev[1];
            }
            s_s[h0] = a0; s_s[h0+1] = a1;
        }
        __syncthreads();
        {
            f32x4 sf[4];
            #pragma unroll
            for (int q = 0; q < 2; ++q) {
                sf[2*q]   = *(const f32x4*)&s_s[q*512 + lane*8];
                sf[2*q+1] = *(const f32x4*)&s_s[q*512 + lane*8 + 4];
            }
            for (int r = 0; r < 128; ++r) {
                const int d = w * 128 + r;
                const float* wr = W + (size_t)d * 1024;
                float sum = 0.f;
                #pragma unroll
                for (int q = 0; q < 2; ++q) {
                    f32x4 w0 = *(const f32x4*)(wr + q*512 + lane*8);
                    f32x4 w1 = *(const f32x4*)(wr + q*512 + lane*8 + 4);
                    #pragma unroll
                    for (int j = 0; j < 4; ++j) {
                        sum += w0[j] * sf[2*q][j];
                        sum += w1[j] * sf[2*q+1][j];
                    }
                }
                #pragma unroll
                for (int off = 32; off; off >>= 1) sum += __shfl_xor(sum, off, 64);
                if (lane == 0) chat_s[d] = sum;
            }
        }
        __syncthreads();
        {
            const int h0 = t * 2;
            float v0 = chat_s[h0], v1 = chat_s[h0+1];
            float ss = v0*v0 + v1*v1;
            #pragma unroll
            for (int off = 32; off; off >>= 1) ss += __shfl_xor(ss, off, 64);
            if (lane == 0) red_s[w] = ss;
            __syncthreads();
            float norm = 0.f;
            #pragma unroll
            for (int i = 0; i < 8; ++i) norm += red_s[i];
            const float scale = norm / ((1.f + norm) * sqrtf(norm) + 1e-30f);
            c_s[h0] = v0 * scale; c_s[h0+1] = v1 * scale;
        }
        __syncthreads();
        if (it < 2) {
            const int h0 = t * 2;
            float uu0 = 0.f, uu1 = 0.f;
            for (int d = 0; d < 1024; ++d) {
                f32x2 wv = *(const f32x2*)(W + (size_t)d * 1024 + h0);
                uu0 += c_s[d] * wv[0]; uu1 += c_s[d] * wv[1];
            }
            u_s[h0] = uu0; u_s[h0+1] = uu1;
        } else {
            const int h0 = t * 2;
            f32x2 ov; ov[0] = c_s[h0]; ov[1] = c_s[h0+1];
            *(f32x2*)(outp + (size_t)blockIdx.x * 1024 + h0) = ov;
        }
        __syncthreads();
    }
}

extern "C" void kernel_launch(void* const* d_in, const int* in_sizes, int n_in,
                              void* d_out, int out_size, void* d_ws, size_t ws_size,
                              hipStream_t stream)
{
    const float* enc = (const float*)d_in[0];   // [256,64,1024] fp32
    const float* W   = (const float*)d_in[1];   // [1024,1024]   fp32
    float* outp = (float*)d_out;                // [256,1024]    fp32
    (void)in_sizes; (void)n_in; (void)out_size;

    // ws layout (11.5 MB)
    char* ws = (char*)d_ws;
    float*  b     = (float*) (ws + 0x000000);  //  64 KB [256,64]
    __bf16* s_hi  = (__bf16*)(ws + 0x080000);  // 512 KB [256,1024]
    __bf16* s_lo  = (__bf16*)(ws + 0x100000);  // 512 KB
    float*  y0    = (float*) (ws + 0x180000);  //   1 MB (y / chat, split-K lo)
    float*  y1    = (float*) (ws + 0x280000);  //   1 MB (y / chat, split-K hi)
    __bf16* Wx_hi = (__bf16*)(ws + 0x380000);  //   2 MB  Wt then Wb (reuse)
    __bf16* Wx_lo = (__bf16*)(ws + 0x580000);  //   2 MB
    __bf16* Q_hi  = (__bf16*)(ws + 0x780000);  //   2 MB [1024,1024]
    __bf16* Q_lo  = (__bf16*)(ws + 0x980000);  //   2 MB

    if (ws_size < 0xB80000) {
        fallback_kernel<<<256, 512, 0, stream>>>(enc, W, outp);
        return;
    }

    // D1: W -> Wt split-bf16 (transposed layout, feeds Q-GEMM)
    convert_wt_kernel<<<dim3(16, 16), 256, 0, stream>>>(W, Wx_hi, Wx_lo);

    // D2: Q = Wt Wt^T (standalone, L2-warm Wt)
    gemm_q_kernel<<<256, 256, 0, stream>>>(Wx_hi, Wx_lo, Q_hi, Q_lo);

    // D3: routing iter0 (s = mean_k enc)
    routing_kernel<0><<<256, 1024, 0, stream>>>(enc, y0, y1, b, s_hi, s_lo);

    // D4: y = Q s  || convert W -> Wb into the (now dead) Wt buffer
    gemm_split_kernel<1><<<768, 256, 0, stream>>>(
        s_hi, s_lo, Q_hi, Q_lo, y0, y1, W, Wx_hi, Wx_lo);

    // D5: routing iter1 (norm = s.y -> scale; b = scale*(E.y); new s)
    routing_kernel<1><<<256, 1024, 0, stream>>>(enc, y0, y1, b, s_hi, s_lo);

    // D6: y = Q s
    gemm_split_kernel<0><<<512, 256, 0, stream>>>(
        s_hi, s_lo, Q_hi, Q_lo, y0, y1, nullptr, nullptr, nullptr);

    // D7: routing iter2 (b += scale*(E.y); final s)
    routing_kernel<2><<<256, 1024, 0, stream>>>(enc, y0, y1, b, s_hi, s_lo);

    // D8: chat = W s   (B = Wb, now in Wx)
    gemm_split_kernel<0><<<512, 256, 0, stream>>>(
        s_hi, s_lo, Wx_hi, Wx_lo, y0, y1, nullptr, nullptr, nullptr);

    // D9: out = squash(chat)
    squash_out_kernel<<<256, 256, 0, stream>>>(y0, y1, outp);
}

// Round 5
// 186.020 us; speedup vs baseline: 1.5584x; 1.0710x over previous
//
#include <hip/hip_runtime.h>

// InductionNetwork capsule routing, C=256, K=64, H=1024, 3 iterations.
// R12: R11 hit 199us but top-5 counters were all harness fills -> every
// kernel <41us. Largest modeled waste: un-tiled gemm_split (2048 waves x
// private 64KB K-panels = 128 MB cache traffic per GEMM dispatch x4).
// R12: (1) y/chat GEMMs tiled 64x64 + split-K x2, BK=64 LDS-staged with
// XOR swizzle (32 MB traffic, 4x less); (2) convert_wt merged into the
// routing0 dispatch (9 -> 8 dispatches). Routing untouched (control).
// Dispatches (8):
//   A convwt||routing0   W -> Wt split-bf16 ; s = mean_k enc
//   B gemm_Q             Q = Wt Wt^T (256 x 64x64 LDS tiles)
//   C gemm_y0||convWb    y = Q s (tiled) ; W -> Wb into Wx (Wt dead)
//   D routing1           norm=s.y -> scale; b = scale*(E.y); s
//   E gemm_y1            y = Q s (tiled)
//   F routing2           b += scale*(E.y); s
//   G gemm_chat          chat = W s (tiled, B = Wb)
//   H squash_out         out = squash(chat)
// Split-bf16 operands (verified R6-R11, absmax 4.88e-4):
//   D = Ah.Bh + Ah.Bl + Al.Bh with hi=bf16(x), lo=bf16(x-hi).
// Fragment layout verified R4/R6/R7: A[m=lane&15][k=(lane>>4)*8+j];
// C/D col=lane&15, row=(lane>>4)*4+reg.
// Fallback: R3's proven monolithic kernel if ws too small.

using f32x4  = __attribute__((ext_vector_type(4))) float;
using f32x2  = __attribute__((ext_vector_type(2))) float;
using bf16x8 = __attribute__((ext_vector_type(8))) __bf16;
using bf16x4 = __attribute__((ext_vector_type(4))) __bf16;

struct BfPair { __bf16 hi, lo; };
__device__ inline BfPair split_bf16(float x) {
    BfPair p;
    p.hi = (__bf16)x;
    p.lo = (__bf16)(x - (float)p.hi);
    return p;
}

// ---------------- shared LDS shapes ----------------------------------------
struct RoutSM {
    float spart[16][1024];  // 64 KB: per-wave partial s
    float u_s[1024];        //  4 KB: y staged for the dots
    float b_s[64], d_s[64], red_s[16], scale_s;
};

// ---------------- routing body (verified R11) ------------------------------
// One block per capsule, 1024 threads = 16 waves, 1 block/CU. Wave w owns
// enc rows w*4..w*4+3; lane holds 16 floats/row (64 VGPRs, pinned).
// MODE 0: d uniform (iter 0). MODE 1: b = scale*(E.y). MODE 2: b += ...
template <int MODE>
__device__ __forceinline__ void routing_body(
    int c, const float* __restrict__ enc, const float* __restrict__ y0,
    const float* __restrict__ y1, float* __restrict__ bglob,
    __bf16* __restrict__ s_hi, __bf16* __restrict__ s_lo, RoutSM* sm)
{
    const int t = threadIdx.x, lane = t & 63, w = t >> 6;   // 16 waves
    const float* E = enc + (size_t)c * 65536;

    // small prologue loads first so their waitcnt doesn't drain er loads
    float yv = 0.f, sv = 0.f;
    if (MODE > 0) {
        const size_t o = (size_t)c * 1024 + t;
        yv = y0[o] + y1[o];                       // y = Q s (full K)
        sv = (float)s_hi[o] + (float)s_lo[o];     // s as the gemm saw it
    }

    f32x4 er[4][4];                     // 64 VGPRs of enc
    #pragma unroll
    for (int r = 0; r < 4; ++r) {
        const float* ek = E + (size_t)(w * 4 + r) * 1024 + lane * 8;
        er[r][0] = *(const f32x4*)(ek);
        er[r][1] = *(const f32x4*)(ek + 4);
        er[r][2] = *(const f32x4*)(ek + 512);
        er[r][3] = *(const f32x4*)(ek + 516);
    }
    // Pin er in VGPRs: opaque defs the compiler cannot rematerialize by
    // re-loading from global after the barrier (R10: VGPR_Count=36 showed
    // the enc tile was never actually register-resident).
    #pragma unroll
    for (int r = 0; r < 4; ++r)
        #pragma unroll
        for (int q = 0; q < 4; ++q)
            asm volatile("" : "+v"(er[r][q]));

    if (MODE > 0) {
        sm->u_s[t] = yv;
        float p = yv * sv;                        // norm = s^T Q s = |W s|^2
        #pragma unroll
        for (int off = 32; off; off >>= 1) p += __shfl_xor(p, off, 64);
        if (lane == 0) sm->red_s[w] = p;
        __syncthreads();
        if (t == 0) {
            float n = 0.f;
            #pragma unroll
            for (int i = 0; i < 16; ++i) n += sm->red_s[i];
            sm->scale_s = n / ((1.f + n) * sqrtf(n) + 1e-30f);
        }
        __syncthreads();
        const float scale = sm->scale_s;
        f32x4 uf[4];
        uf[0] = *(const f32x4*)&sm->u_s[lane * 8];
        uf[1] = *(const f32x4*)&sm->u_s[lane * 8 + 4];
        uf[2] = *(const f32x4*)&sm->u_s[512 + lane * 8];
        uf[3] = *(const f32x4*)&sm->u_s[512 + lane * 8 + 4];
        #pragma unroll
        for (int r = 0; r < 4; ++r) {
            float sum = 0.f;
            #pragma unroll
            for (int q = 0; q < 4; ++q)
                #pragma unroll
                for (int j = 0; j < 4; ++j)
                    sum += er[r][q][j] * uf[q][j];
            #pragma unroll
            for (int off = 32; off; off >>= 1) sum += __shfl_xor(sum, off, 64);
            if (lane == 0) {
                const int k = w * 4 + r;
                const float bv =
                    (MODE == 2 ? bglob[c * 64 + k] : 0.f) + scale * sum;
                bglob[c * 64 + k] = bv;     // persist for next iteration
                sm->b_s[k] = bv;
            }
        }
    }
    __syncthreads();

    if (MODE == 0) {
        if (t < 64) sm->d_s[t] = 1.f / 64.f;
    } else if (t < 64) {
        float bv = sm->b_s[t], m = bv;
        #pragma unroll
        for (int off = 32; off; off >>= 1) m = fmaxf(m, __shfl_xor(m, off, 64));
        const float e = expf(bv - m);
        float smm = e;
        #pragma unroll
        for (int off = 32; off; off >>= 1) smm += __shfl_xor(smm, off, 64);
        sm->d_s[t] = e / smm;
    }
    __syncthreads();

    // per-wave partial s from registers (4 rows each)
    #pragma unroll
    for (int q = 0; q < 4; ++q) {
        f32x4 p = {};
        #pragma unroll
        for (int r = 0; r < 4; ++r) {
            const float dk = sm->d_s[w * 4 + r];
            #pragma unroll
            for (int j = 0; j < 4; ++j) p[j] += dk * er[r][q][j];
        }
        const int h = (q >> 1) * 512 + lane * 8 + (q & 1) * 4;
        *(f32x4*)&sm->spart[w][h] = p;
    }
    __syncthreads();

    // cross-wave reduce: 1 h-element per thread; emit split-bf16 s
    {
        float a = 0.f;
        #pragma unroll
        for (int wv = 0; wv < 16; ++wv) a += sm->spart[wv][t];
        const BfPair p = split_bf16(a);
        s_hi[(size_t)c * 1024 + t] = p.hi;
        s_lo[(size_t)c * 1024 + t] = p.lo;
    }
}

// Routing dispatch. WITH_CONV: blocks [0,256) do W -> Wt split-bf16
// (transposed, 64x64 LDS tiles); routing capsules are blocks [256,512).
template <int MODE, int WITH_CONV>
__global__ __launch_bounds__(1024, 4) void routing_kernel(
    const float* __restrict__ enc, const float* __restrict__ y0,
    const float* __restrict__ y1, float* __restrict__ bglob,
    __bf16* __restrict__ s_hi, __bf16* __restrict__ s_lo,
    const float* __restrict__ W, __bf16* __restrict__ Wt_hi,
    __bf16* __restrict__ Wt_lo)
{
    __shared__ union {
        RoutSM r;
        float tile[64][65];     // 16.6 KB: conv transpose staging
    } sm;

    int c = blockIdx.x;
    if (WITH_CONV) {
        if (blockIdx.x < 256) {
            const int by = blockIdx.x >> 4, bx = blockIdx.x & 15;
            const int tx = threadIdx.x & 63, ty = threadIdx.x >> 6;
            for (int i = ty; i < 64; i += 16)
                sm.tile[i][tx] = W[(size_t)(by * 64 + i) * 1024 + bx * 64 + tx];
            __syncthreads();
            for (int i = ty; i < 64; i += 16) {
                const size_t idx = (size_t)(bx * 64 + i) * 1024 + by * 64 + tx;
                const BfPair p = split_bf16(sm.tile[tx][i]);
                Wt_hi[idx] = p.hi;
                Wt_lo[idx] = p.lo;
            }
            return;
        }
        c = blockIdx.x - 256;
    }
    routing_body<MODE>(c, enc, y0, y1, bglob, s_hi, s_lo, &sm.r);
}

// ---------------- LDS-tiled GEMM machinery ---------------------------------
struct QSmem {
    __bf16 a_hi[64 * 64];
    __bf16 a_lo[64 * 64];
    __bf16 b_hi[64 * 64];
    __bf16 b_lo[64 * 64];
};

__device__ __forceinline__ int swz128(int row, int colbyte) {
    // 128-byte rows; XOR bits 4-6 of the byte offset with row&7
    return row * 128 + (colbyte ^ ((row & 7) << 4));
}

// ---- Q = Wt Wt^T (= W^T W): 256 blocks (16x16 tile grid), 256 threads =
// 4 waves in a 2x2 grid, each wave a 32x32 sub-tile (2x2 16x16 frags),
// BK=64 LDS staging, XOR-swizzled rows. Writes split-bf16 Q. (verified R11)
__global__ __launch_bounds__(256) void gemm_q_kernel(
    const __bf16* __restrict__ Wt_hi, const __bf16* __restrict__ Wt_lo,
    __bf16* __restrict__ Q_hi, __bf16* __restrict__ Q_lo)
{
    __shared__ QSmem sm;
    const int qb = blockIdx.x;
    const int ti = qb >> 4, tj = qb & 15;       // 16x16 grid of 64x64 tiles
    const int t = threadIdx.x;
    const int lane = t & 63, w = t >> 6;        // 4 waves
    const int wr = w >> 1, wc = w & 1;          // wave's 32x32 sub-tile
    const int sr  = t >> 2;                     // row 0..63
    const int scb = (t & 3) * 16;               // col byte {0,16,32,48}
    const size_t ga = (size_t)(ti * 64 + sr) * 1024 + scb / 2;
    const size_t gb = (size_t)(tj * 64 + sr) * 1024 + scb / 2;

    f32x4 acc[2][2] = {};
    for (int k0 = 0; k0 < 1024; k0 += 64) {
        if (k0) __syncthreads();                // prev step's reads done
        #pragma unroll
        for (int h = 0; h < 2; ++h) {
            const int cb = scb + h * 64;        // covers full 128-B row
            const size_t gao = ga + h * 32 + k0;
            const size_t gbo = gb + h * 32 + k0;
            *(bf16x8*)((char*)sm.a_hi + swz128(sr, cb)) = *(const bf16x8*)(Wt_hi + gao);
            *(bf16x8*)((char*)sm.a_lo + swz128(sr, cb)) = *(const bf16x8*)(Wt_lo + gao);
            *(bf16x8*)((char*)sm.b_hi + swz128(sr, cb)) = *(const bf16x8*)(Wt_hi + gbo);
            *(bf16x8*)((char*)sm.b_lo + swz128(sr, cb)) = *(const bf16x8*)(Wt_lo + gbo);
        }
        __syncthreads();
        #pragma unroll
        for (int kk = 0; kk < 2; ++kk) {
            const int cb = kk * 64 + (lane >> 4) * 16;  // col byte of frag
            bf16x8 ah[2], al[2], bh[2], bl[2];
            #pragma unroll
            for (int mi = 0; mi < 2; ++mi) {
                const int m = wr * 32 + mi * 16 + (lane & 15);
                ah[mi] = *(const bf16x8*)((char*)sm.a_hi + swz128(m, cb));
                al[mi] = *(const bf16x8*)((char*)sm.a_lo + swz128(m, cb));
            }
            #pragma unroll
            for (int ni = 0; ni < 2; ++ni) {
                const int n = wc * 32 + ni * 16 + (lane & 15);
                bh[ni] = *(const bf16x8*)((char*)sm.b_hi + swz128(n, cb));
                bl[ni] = *(const bf16x8*)((char*)sm.b_lo + swz128(n, cb));
            }
            #pragma unroll
            for (int mi = 0; mi < 2; ++mi)
                #pragma unroll
                for (int ni = 0; ni < 2; ++ni) {
                    f32x4 a = acc[mi][ni];
                    a = __builtin_amdgcn_mfma_f32_16x16x32_bf16(ah[mi], bh[ni], a, 0, 0, 0);
                    a = __builtin_amdgcn_mfma_f32_16x16x32_bf16(ah[mi], bl[ni], a, 0, 0, 0);
                    a = __builtin_amdgcn_mfma_f32_16x16x32_bf16(al[mi], bh[ni], a, 0, 0, 0);
                    acc[mi][ni] = a;
                }
        }
    }
    const int rr = (lane >> 4) * 4, colb = lane & 15;
    #pragma unroll
    for (int mi = 0; mi < 2; ++mi)
        #pragma unroll
        for (int ni = 0; ni < 2; ++ni)
            #pragma unroll
            for (int r = 0; r < 4; ++r) {
                const BfPair p = split_bf16(acc[mi][ni][r]);
                const size_t idx =
                    (size_t)(ti * 64 + wr * 32 + mi * 16 + rr + r) * 1024 +
                    tj * 64 + wc * 32 + ni * 16 + colb;
                Q_hi[idx] = p.hi;
                Q_lo[idx] = p.lo;
            }
}

// ---- tiled split-bf16 NT GEMM, split-K x2: C[256,1024] = A[256,:] B^T.
// 128 blocks: kh = bx&1, task = bx>>1 -> mt (4 x 64 rows), nt (16 x 64
// cols). 256 thr = 4 waves (2x2 of 32x32). BK=64 LDS staging, swizzled.
// With CONV, blocks [128,384) convert W fp32 -> split-bf16 Wd (coalesced).
template <int CONV>
__global__ __launch_bounds__(256) void gemm_nt_kernel(
    const __bf16* __restrict__ Ah, const __bf16* __restrict__ Al,
    const __bf16* __restrict__ Bh, const __bf16* __restrict__ Bl,
    float* __restrict__ C0, float* __restrict__ C1,
    const float* __restrict__ Wsrc, __bf16* __restrict__ Wd_hi,
    __bf16* __restrict__ Wd_lo)
{
    __shared__ QSmem sm;
    if (CONV && blockIdx.x >= 128) {
        const int b = blockIdx.x - 128;             // 0..255
        const size_t base = (size_t)b * 4096 + (threadIdx.x << 2);
        #pragma unroll
        for (int q = 0; q < 4; ++q) {
            const size_t idx = base + (size_t)q * 1024;
            const f32x4 v = *(const f32x4*)(Wsrc + idx);
            bf16x4 hv, lv;
            #pragma unroll
            for (int j = 0; j < 4; ++j) {
                const BfPair p = split_bf16(v[j]);
                hv[j] = p.hi;
                lv[j] = p.lo;
            }
            *(bf16x4*)(Wd_hi + idx) = hv;
            *(bf16x4*)(Wd_lo + idx) = lv;
        }
        return;
    }

    const int kh   = blockIdx.x & 1;
    const int task = blockIdx.x >> 1;
    const int mt   = task >> 4;                 // 0..3   (64-row panel)
    const int nt   = task & 15;                 // 0..15  (64-col panel)
    const int t = threadIdx.x;
    const int lane = t & 63, w = t >> 6;        // 4 waves
    const int wr = w >> 1, wc = w & 1;          // wave's 32x32 sub-tile
    const int sr  = t >> 2;                     // row 0..63
    const int scb = (t & 3) * 16;               // col byte {0,16,32,48}
    const size_t ga = (size_t)(mt * 64 + sr) * 1024 + kh * 512 + scb / 2;
    const size_t gb = (size_t)(nt * 64 + sr) * 1024 + kh * 512 + scb / 2;

    f32x4 acc[2][2] = {};
    for (int k0 = 0; k0 < 512; k0 += 64) {
        if (k0) __syncthreads();                // prev step's reads done
        #pragma unroll
        for (int h = 0; h < 2; ++h) {
            const int cb = scb + h * 64;        // covers full 128-B row
            const size_t gao = ga + h * 32 + k0;
            const size_t gbo = gb + h * 32 + k0;
            *(bf16x8*)((char*)sm.a_hi + swz128(sr, cb)) = *(const bf16x8*)(Ah + gao);
            *(bf16x8*)((char*)sm.a_lo + swz128(sr, cb)) = *(const bf16x8*)(Al + gao);
            *(bf16x8*)((char*)sm.b_hi + swz128(sr, cb)) = *(const bf16x8*)(Bh + gbo);
            *(bf16x8*)((char*)sm.b_lo + swz128(sr, cb)) = *(const bf16x8*)(Bl + gbo);
        }
        __syncthreads();
        #pragma unroll
        for (int kk = 0; kk < 2; ++kk) {
            const int cb = kk * 64 + (lane >> 4) * 16;  // col byte of frag
            bf16x8 ah[2], al[2], bh[2], bl[2];
            #pragma unroll
            for (int mi = 0; mi < 2; ++mi) {
                const int m = wr * 32 + mi * 16 + (lane & 15);
                ah[mi] = *(const bf16x8*)((char*)sm.a_hi + swz128(m, cb));
                al[mi] = *(const bf16x8*)((char*)sm.a_lo + swz128(m, cb));
            }
            #pragma unroll
            for (int ni = 0; ni < 2; ++ni) {
                const int n = wc * 32 + ni * 16 + (lane & 15);
                bh[ni] = *(const bf16x8*)((char*)sm.b_hi + swz128(n, cb));
                bl[ni] = *(const bf16x8*)((char*)sm.b_lo + swz128(n, cb));
            }
            #pragma unroll
            for (int mi = 0; mi < 2; ++mi)
                #pragma unroll
                for (int ni = 0; ni < 2; ++ni) {
                    f32x4 a = acc[mi][ni];
                    a = __builtin_amdgcn_mfma_f32_16x16x32_bf16(ah[mi], bh[ni], a, 0, 0, 0);
                    a = __builtin_amdgcn_mfma_f32_16x16x32_bf16(ah[mi], bl[ni], a, 0, 0, 0);
                    a = __builtin_amdgcn_mfma_f32_16x16x32_bf16(al[mi], bh[ni], a, 0, 0, 0);
                    acc[mi][ni] = a;
                }
        }
    }
    float* Cc = kh ? C1 : C0;
    const int rr = (lane >> 4) * 4, colb = lane & 15;
    #pragma unroll
    for (int mi = 0; mi < 2; ++mi)
        #pragma unroll
        for (int ni = 0; ni < 2; ++ni)
            #pragma unroll
            for (int r = 0; r < 4; ++r)
                Cc[(size_t)(mt * 64 + wr * 32 + mi * 16 + rr + r) * 1024 +
                   nt * 64 + wc * 32 + ni * 16 + colb] = acc[mi][ni][r];
}

// ---------------- final squash: sums split-K chat, emits out ---------------
__global__ __launch_bounds__(256) void squash_out_kernel(
    const float* __restrict__ chat0, const float* __restrict__ chat1,
    float* __restrict__ outp)
{
    __shared__ float wsum[4];
    const int c = blockIdx.x, t = threadIdx.x;
    const int lane = t & 63, w = t >> 6;
    const size_t o = (size_t)c * 1024 + t * 4;
    f32x4 v = *(const f32x4*)(chat0 + o) + *(const f32x4*)(chat1 + o);
    float ss = v[0]*v[0] + v[1]*v[1] + v[2]*v[2] + v[3]*v[3];
    #pragma unroll
    for (int off = 32; off; off >>= 1) ss += __shfl_xor(ss, off, 64);
    if (lane == 0) wsum[w] = ss;
    __syncthreads();
    const float norm = wsum[0] + wsum[1] + wsum[2] + wsum[3];
    const float scale = norm / ((1.f + norm) * sqrtf(norm) + 1e-30f);
    *(f32x4*)(outp + o) = v * scale;
}

// ---------------- fallback: R3's proven monolithic fp32 kernel --------------
__global__ __launch_bounds__(512) void fallback_kernel(
    const float* __restrict__ enc, const float* __restrict__ W,
    float* __restrict__ outp)
{
    __shared__ float u_s[1024], s_s[1024], c_s[1024], chat_s[1024];
    __shared__ float b_s[64], d_s[64], red_s[8];
    const int t = threadIdx.x, lane = t & 63, w = t >> 6;
    const float* erow = enc + (size_t)blockIdx.x * 65536;

    if (t < 64) b_s[t] = 0.f;
    __syncthreads();

    for (int it = 0; it < 3; ++it) {
        if (it > 0) {
            f32x4 uf[4];
            #pragma unroll
            for (int q = 0; q < 2; ++q) {
                uf[2*q]   = *(const f32x4*)&u_s[q*512 + lane*8];
                uf[2*q+1] = *(const f32x4*)&u_s[q*512 + lane*8 + 4];
            }
            for (int r = 0; r < 8; ++r) {
                const int k = w * 8 + r;
                const float* ek = erow + (size_t)k * 1024;
                float sum = 0.f;
                #pragma unroll
                for (int q = 0; q < 2; ++q) {
                    f32x4 e0 = *(const f32x4*)(ek + q*512 + lane*8);
                    f32x4 e1 = *(const f32x4*)(ek + q*512 + lane*8 + 4);
                    #pragma unroll
                    for (int j = 0; j < 4; ++j) {
                        sum += e0[j] * uf[2*q][j];
                        sum += e1[j] * uf[2*q+1][j];
                    }
                }
                #pragma unroll
                for (int off = 32; off; off >>= 1) sum += __shfl_xor(sum, off, 64);
                if (lane == 0) b_s[k] += sum;
            }
            __syncthreads();
        }
        if (t < 64) {
            float bv = b_s[t], m = bv;
            #pragma unroll
            for (int off = 32; off; off >>= 1) m = fmaxf(m, __shfl_xor(m, off, 64));
            float e = expf(bv - m), sm = e;
            #pragma unroll
            for (int off = 32; off; off >>= 1) sm += __shfl_xor(sm, off, 64);
            d_s[t] = e / sm;
        }
        __syncthreads();
        {
            const int h0 = t * 2;
            float a0 = 0.f, a1 = 0.f;
            for (int k = 0; k < 64; ++k) {
                f32x2 ev = *(const f32x2*)(erow + (size_t)k * 1024 + h0);
                a0 += d_s[k] * ev[0]; a1 += d_s[k] * ev[1];
            }
            s_s[h0] = a0; s_s[h0+1] = a1;
        }
        __syncthreads();
        {
            f32x4 sf[4];
            #pragma unroll
            for (int q = 0; q < 2; ++q) {
                sf[2*q]   = *(const f32x4*)&s_s[q*512 + lane*8];
                sf[2*q+1] = *(const f32x4*)&s_s[q*512 + lane*8 + 4];
            }
            for (int r = 0; r < 128; ++r) {
                const int d = w * 128 + r;
                const float* wr = W + (size_t)d * 1024;
                float sum = 0.f;
                #pragma unroll
                for (int q = 0; q < 2; ++q) {
                    f32x4 w0 = *(const f32x4*)(wr + q*512 + lane*8);
                    f32x4 w1 = *(const f32x4*)(wr + q*512 + lane*8 + 4);
                    #pragma unroll
                    for (int j = 0; j < 4; ++j) {
                        sum += w0[j] * sf[2*q][j];
                        sum += w1[j] * sf[2*q+1][j];
                    }
                }
                #pragma unroll
                for (int off = 32; off; off >>= 1) sum += __shfl_xor(sum, off, 64);
                if (lane == 0) chat_s[d] = sum;
            }
        }
        __syncthreads();
        {
            const int h0 = t * 2;
            float v0 = chat_s[h0], v1 = chat_s[h0+1];
            float ss = v0*v0 + v1*v1;
            #pragma unroll
            for (int off = 32; off; off >>= 1) ss += __shfl_xor(ss, off, 64);
            if (lane == 0) red_s[w] = ss;
            __syncthreads();
            float norm = 0.f;
            #pragma unroll
            for (int i = 0; i < 8; ++i) norm += red_s[i];
            const float scale = norm / ((1.f + norm) * sqrtf(norm) + 1e-30f);
            c_s[h0] = v0 * scale; c_s[h0+1] = v1 * scale;
        }
        __syncthreads();
        if (it < 2) {
            const int h0 = t * 2;
            float uu0 = 0.f, uu1 = 0.f;
            for (int d = 0; d < 1024; ++d) {
                f32x2 wv = *(const f32x2*)(W + (size_t)d * 1024 + h0);
                uu0 += c_s[d] * wv[0]; uu1 += c_s[d] * wv[1];
            }
            u_s[h0] = uu0; u_s[h0+1] = uu1;
        } else {
            const int h0 = t * 2;
            f32x2 ov; ov[0] = c_s[h0]; ov[1] = c_s[h0+1];
            *(f32x2*)(outp + (size_t)blockIdx.x * 1024 + h0) = ov;
        }
        __syncthreads();
    }
}

extern "C" void kernel_launch(void* const* d_in, const int* in_sizes, int n_in,
                              void* d_out, int out_size, void* d_ws, size_t ws_size,
                              hipStream_t stream)
{
    const float* enc = (const float*)d_in[0];   // [256,64,1024] fp32
    const float* W   = (const float*)d_in[1];   // [1024,1024]   fp32
    float* outp = (float*)d_out;                // [256,1024]    fp32
    (void)in_sizes; (void)n_in; (void)out_size;

    // ws layout (11.5 MB)
    char* ws = (char*)d_ws;
    float*  b     = (float*) (ws + 0x000000);  //  64 KB [256,64]
    __bf16* s_hi  = (__bf16*)(ws + 0x080000);  // 512 KB [256,1024]
    __bf16* s_lo  = (__bf16*)(ws + 0x100000);  // 512 KB
    float*  y0    = (float*) (ws + 0x180000);  //   1 MB (y / chat, split-K lo)
    float*  y1    = (float*) (ws + 0x280000);  //   1 MB (y / chat, split-K hi)
    __bf16* Wx_hi = (__bf16*)(ws + 0x380000);  //   2 MB  Wt then Wb (reuse)
    __bf16* Wx_lo = (__bf16*)(ws + 0x580000);  //   2 MB
    __bf16* Q_hi  = (__bf16*)(ws + 0x780000);  //   2 MB [1024,1024]
    __bf16* Q_lo  = (__bf16*)(ws + 0x980000);  //   2 MB

    if (ws_size < 0xB80000) {
        fallback_kernel<<<256, 512, 0, stream>>>(enc, W, outp);
        return;
    }

    // A: convert_wt (blocks 0..255) || routing iter0 (blocks 256..511)
    routing_kernel<0, 1><<<512, 1024, 0, stream>>>(
        enc, y0, y1, b, s_hi, s_lo, W, Wx_hi, Wx_lo);

    // B: Q = Wt Wt^T
    gemm_q_kernel<<<256, 256, 0, stream>>>(Wx_hi, Wx_lo, Q_hi, Q_lo);

    // C: y = Q s (tiled)  || convert W -> Wb into the (now dead) Wt buffer
    gemm_nt_kernel<1><<<384, 256, 0, stream>>>(
        s_hi, s_lo, Q_hi, Q_lo, y0, y1, W, Wx_hi, Wx_lo);

    // D: routing iter1 (norm = s.y -> scale; b = scale*(E.y); new s)
    routing_kernel<1, 0><<<256, 1024, 0, stream>>>(
        enc, y0, y1, b, s_hi, s_lo, nullptr, nullptr, nullptr);

    // E: y = Q s (tiled)
    gemm_nt_kernel<0><<<128, 256, 0, stream>>>(
        s_hi, s_lo, Q_hi, Q_lo, y0, y1, nullptr, nullptr, nullptr);

    // F: routing iter2 (b += scale*(E.y); final s)
    routing_kernel<2, 0><<<256, 1024, 0, stream>>>(
        enc, y0, y1, b, s_hi, s_lo, nullptr, nullptr, nullptr);

    // G: chat = W s (tiled, B = Wb in Wx)
    gemm_nt_kernel<0><<<128, 256, 0, stream>>>(
        s_hi, s_lo, Wx_hi, Wx_lo, y0, y1, nullptr, nullptr, nullptr);

    // H: out = squash(chat)
    squash_out_kernel<<<256, 256, 0, stream>>>(y0, y1, outp);
}